// Round 9
// baseline (445.179 us; speedup 1.0000x reference)
//
#include <hip/hip_runtime.h>
#include <hip/hip_bf16.h>
#include <math.h>

#define NM 65536
#define NB 128
#define NU 256
#define ND 512

// ---- output layout (flat f32, reference return order) ----
constexpr size_t OUT_READ = 0;                      // [B,U]    32768
constexpr size_t OUT_MEM  = 32768;                  // [M,U]    16777216
constexpr size_t OUT_CWU  = OUT_MEM + 16777216;     // [M,B]    8388608
constexpr size_t OUT_CWLU = OUT_CWU + 8388608;      // [M,B]
constexpr size_t OUT_CWR  = OUT_CWLU + 8388608;     // [M,B]
constexpr size_t OUT_KEY  = OUT_CWR + 8388608;      // [B,U]
constexpr size_t OUT_CC   = OUT_KEY + 32768;        // [B,U]

// ---- ws layout (bytes) ----
constexpr size_t WS_KLNT   = 0;        // 32768 f32 (klnT[u][b])
constexpr size_t WS_MINENC = 131072;   // 128 u64
constexpr size_t WS_MINS   = 132096;   // 128 f32
constexpr size_t WS_ISTAR  = 132608;   // 1 u32
constexpr size_t WS_PART   = 135168;   // 512 * 16384 f32 read-partials (32 MB)

typedef __attribute__((ext_vector_type(8))) short short8v;   // 8 bf16 (4 VGPRs)
typedef __attribute__((ext_vector_type(4))) float floatx4;

__device__ __forceinline__ unsigned fenc(float x) {
    unsigned u = __float_as_uint(x);
    return (u & 0x80000000u) ? ~u : (u | 0x80000000u);
}
__device__ __forceinline__ float fdec(unsigned e) {
    unsigned u = (e & 0x80000000u) ? (e ^ 0x80000000u) : ~e;
    return __uint_as_float(u);
}
__device__ __forceinline__ float sigm(float x) { return 1.0f / (1.0f + expf(-x)); }
__device__ __forceinline__ unsigned short f2b(float f) {
    __hip_bfloat16 h = __float2bfloat16(f);      // RNE
    return *reinterpret_cast<unsigned short*>(&h);
}

// ---------------- K1: LSTM controller + normalized keys (UNCHANGED, numerics anchor) ----------------
__global__ __launch_bounds__(256) void k_lstm(
    const float* __restrict__ xin_g, const float* __restrict__ r_tm1,
    const float* __restrict__ h_tm1, const float* __restrict__ cc_tm1,
    const float* __restrict__ Wk, const float* __restrict__ Wr,
    const float* __restrict__ bias, float* __restrict__ out,
    float* __restrict__ klnT, unsigned long long* __restrict__ minenc)
{
    const int b = blockIdx.x, t = threadIdx.x;
    __shared__ float xin[ND + NU];
    __shared__ float hh[NU];
    __shared__ float red[NU];
    for (int k = t; k < ND; k += 256) xin[k] = xin_g[b * ND + k];
    xin[ND + t] = r_tm1[b * NU + t];
    hh[t] = h_tm1[b * NU + t];
    out[OUT_READ + b * NU + t] = 0.f;              // zero read region each launch
    if (b == 0 && t < NB) minenc[t] = ~0ULL;       // init argmin atomics
    __syncthreads();

    float zi = bias[t], zf = bias[NU + t], zc = bias[2 * NU + t], zo = bias[3 * NU + t];
    #pragma unroll 4
    for (int k = 0; k < ND + NU; ++k) {
        const float x = xin[k];
        const float* w = Wk + (size_t)k * (4 * NU);
        zi += x * w[t]; zf += x * w[NU + t]; zc += x * w[2 * NU + t]; zo += x * w[3 * NU + t];
    }
    #pragma unroll 4
    for (int k = 0; k < NU; ++k) {
        const float x = hh[k];
        const float* w = Wr + (size_t)k * (4 * NU);
        zi += x * w[t]; zf += x * w[NU + t]; zc += x * w[2 * NU + t]; zo += x * w[3 * NU + t];
    }
    const float gi = sigm(zi), gf = sigm(zf), gc = tanhf(zc), go = sigm(zo);
    const float cold = cc_tm1[b * NU + t];
    const float cn = __fadd_rn(__fmul_rn(gf, cold), __fmul_rn(gi, gc));
    const float hn = __fmul_rn(go, tanhf(cn));
    out[OUT_KEY + b * NU + t] = hn;
    out[OUT_CC + b * NU + t] = cn;
    red[t] = hn * hn;
    __syncthreads();
    for (int s = 128; s > 0; s >>= 1) { if (t < s) red[t] += red[t + s]; __syncthreads(); }
    const float nrm = sqrtf(fmaxf(red[0], 1e-12f));
    klnT[t * NB + b] = hn / nrm;   // transposed [u][b]
}

// ------------- K2 v5: norm + cosine GEMM + batch-softmax + usage + min -------------
// Same arithmetic as R4/R8 (bit-identical outputs), restructured for occupancy:
//  - 32 KB LDS (stage buffers only); dot tile spilled in two 64-slot halves
//    through the same buffers -> 3-4 blocks/CU instead of 2.
//  - Single barrier per K-chunk via 2 LDS buffers + 2 register sets (A/B);
//    every global load issued a full segment before its barrier drain.
__global__ __launch_bounds__(256, 4) void k_dot(
    const float* __restrict__ mT, const float* __restrict__ klnT,
    const float* __restrict__ cwr_t, const float* __restrict__ cwlu_t,
    const float* __restrict__ cwu_t, const float* __restrict__ wgp,
    float* __restrict__ out, unsigned long long* __restrict__ minenc)
{
    __shared__ float smem[8192];       // 32 KB: ms buffers @0/2048, kl @4096/6144; reused as spill
    __shared__ float rn_s[128];
    const int t = threadIdx.x, w = t >> 6, l = t & 63;
    const int tx = t & 15, ty = t >> 4;
    const int b0 = tx * 8, s0 = ty * 8;
    const int sb = blockIdx.x * 128;
    const int sl = t & 127, ug = t >> 7;       // ms stage: slot sl, u-halves
    const int ku_ = t >> 4, kb = (t & 15) * 4; // kl stage

    // ---- issue chunk 0 and 1 loads (set A = even chunks, set B = odd) ----
    float4 gmA[2], gkA[2], gmB[2], gkB[2];
    #pragma unroll
    for (int i = 0; i < 2; ++i) {
        gmA[i] = *(const float4*)(mT + (size_t)(sb + sl) * NU + (ug + 2 * i) * 4);
        gkA[i] = *(const float4*)(klnT + (size_t)ku_ * NB + kb + i * 64);
        gmB[i] = *(const float4*)(mT + (size_t)(sb + sl) * NU + 16 + (ug + 2 * i) * 4);
        gkB[i] = *(const float4*)(klnT + (size_t)(16 + ku_) * NB + kb + i * 64);
    }

    // ---- phase 0: row norms (bit-identical: lane-l float4 + xor tree) ----
    #pragma unroll 4
    for (int i = 0; i < 32; ++i) {
        const int s = w * 32 + i;
        const float4 mv = *(const float4*)(mT + (size_t)(sb + s) * NU + l * 4);
        float ss = mv.x * mv.x + mv.y * mv.y + mv.z * mv.z + mv.w * mv.w;
        #pragma unroll
        for (int d = 1; d < 64; d <<= 1) ss += __shfl_xor(ss, d);
        if (l == 0) rn_s[s] = sqrtf(fmaxf(ss, 1e-12f));   // wave-private write; barriers before read
    }

    // ---- write stage(0) from set A ----
    #pragma unroll
    for (int i = 0; i < 2; ++i) {
        const int uo = (ug + 2 * i) * 4;
        smem[uo * 128 + sl]       = gmA[i].x;
        smem[(uo + 1) * 128 + sl] = gmA[i].y;
        smem[(uo + 2) * 128 + sl] = gmA[i].z;
        smem[(uo + 3) * 128 + sl] = gmA[i].w;
        *(float4*)&smem[4096 + ku_ * 128 + kb + i * 64] = gkA[i];
    }

    float acc[8][8];
    #pragma unroll
    for (int i = 0; i < 8; ++i)
        #pragma unroll
        for (int j = 0; j < 8; ++j) acc[i][j] = 0.f;

    // ---- K loop: one barrier per chunk ----
    for (int c = 0; c < 16; ++c) {
        __syncthreads();                       // stage(c) visible; drains load(c+1)/(c+2) harmlessly
        // issue load(c+2) into the set that held chunk c (already staged)
        if (c < 14) {
            const int uc = (c + 2) * 16;
            if ((c & 1) == 0) {
                #pragma unroll
                for (int i = 0; i < 2; ++i) {
                    gmA[i] = *(const float4*)(mT + (size_t)(sb + sl) * NU + uc + (ug + 2 * i) * 4);
                    gkA[i] = *(const float4*)(klnT + (size_t)(uc + ku_) * NB + kb + i * 64);
                }
            } else {
                #pragma unroll
                for (int i = 0; i < 2; ++i) {
                    gmB[i] = *(const float4*)(mT + (size_t)(sb + sl) * NU + uc + (ug + 2 * i) * 4);
                    gkB[i] = *(const float4*)(klnT + (size_t)(uc + ku_) * NB + kb + i * 64);
                }
            }
        }
        // compute chunk c from buffer (c&1)
        const int mo = (c & 1) * 2048;
        const int ko = 4096 + (c & 1) * 2048;
        #pragma unroll 4
        for (int u = 0; u < 16; ++u) {
            const float4 sv0 = *(const float4*)&smem[mo + u * 128 + s0];
            const float4 sv1 = *(const float4*)&smem[mo + u * 128 + s0 + 4];
            const float4 kv0 = *(const float4*)&smem[ko + u * 128 + b0];
            const float4 kv1 = *(const float4*)&smem[ko + u * 128 + b0 + 4];
            const float sv[8] = {sv0.x, sv0.y, sv0.z, sv0.w, sv1.x, sv1.y, sv1.z, sv1.w};
            const float kv[8] = {kv0.x, kv0.y, kv0.z, kv0.w, kv1.x, kv1.y, kv1.z, kv1.w};
            #pragma unroll
            for (int i = 0; i < 8; ++i)
                #pragma unroll
                for (int j = 0; j < 8; ++j)
                    acc[i][j] += sv[i] * kv[j];   // single fmac chain ascending u per (s,b)
        }
        // write stage(c+1) from the other set (loaded one full segment ago)
        if (c < 15) {
            const int mo1 = ((c + 1) & 1) * 2048;
            const int ko1 = 4096 + ((c + 1) & 1) * 2048;
            if ((c & 1) == 0) {
                #pragma unroll
                for (int i = 0; i < 2; ++i) {
                    const int uo = (ug + 2 * i) * 4;
                    smem[mo1 + uo * 128 + sl]       = gmB[i].x;
                    smem[mo1 + (uo + 1) * 128 + sl] = gmB[i].y;
                    smem[mo1 + (uo + 2) * 128 + sl] = gmB[i].z;
                    smem[mo1 + (uo + 3) * 128 + sl] = gmB[i].w;
                    *(float4*)&smem[ko1 + ku_ * 128 + kb + i * 64] = gkB[i];
                }
            } else {
                #pragma unroll
                for (int i = 0; i < 2; ++i) {
                    const int uo = (ug + 2 * i) * 4;
                    smem[mo1 + uo * 128 + sl]       = gmA[i].x;
                    smem[mo1 + (uo + 1) * 128 + sl] = gmA[i].y;
                    smem[mo1 + (uo + 2) * 128 + sl] = gmA[i].z;
                    smem[mo1 + (uo + 3) * 128 + sl] = gmA[i].w;
                    *(float4*)&smem[ko1 + ku_ * 128 + kb + i * 64] = gkA[i];
                }
            }
        }
    }

    // ---- epilogue: two 64-slot halves through the 32 KB spill (identical math) ----
    const float wg = sigm(wgp[0]);
    const float omw = __fsub_rn(1.f, wg);
    unsigned long long lmin0 = ~0ULL, lmin1 = ~0ULL;
    #pragma unroll
    for (int h = 0; h < 2; ++h) {
        __syncthreads();               // stage buffers / previous half free
        if ((ty >> 3) == h) {          // holders of slots [64h, 64h+64) spill
            const int ls0 = s0 & 63;
            #pragma unroll
            for (int i = 0; i < 8; ++i) {
                *(float4*)&smem[(ls0 + i) * 128 + b0]     = make_float4(acc[i][0], acc[i][1], acc[i][2], acc[i][3]);
                *(float4*)&smem[(ls0 + i) * 128 + b0 + 4] = make_float4(acc[i][4], acc[i][5], acc[i][6], acc[i][7]);
            }
        }
        __syncthreads();
        #pragma unroll 2
        for (int i = 0; i < 16; ++i) {
            const int ls = w * 16 + i;
            const int s = h * 64 + ls;
            const int m = sb + s;
            const float2 dv = *(const float2*)&smem[ls * 128 + 2 * l];
            const float rnv = rn_s[s];
            const float2 wrt = ((const float2*)(cwr_t + (size_t)m * NB))[l];
            const float2 wlu = ((const float2*)(cwlu_t + (size_t)m * NB))[l];
            const float2 wut = ((const float2*)(cwu_t + (size_t)m * NB))[l];
            const float c0 = dv.x / rnv, c1 = dv.y / rnv;
            float mx = fmaxf(c0, c1);
            #pragma unroll
            for (int d = 1; d < 64; d <<= 1) mx = fmaxf(mx, __shfl_xor(mx, d));
            const float e0 = expf(c0 - mx), e1 = expf(c1 - mx);
            float sm = e0 + e1;
            #pragma unroll
            for (int d = 1; d < 64; d <<= 1) sm += __shfl_xor(sm, d);
            const float w0 = e0 / sm, w1 = e1 / sm;
            const float cww0 = __fadd_rn(__fadd_rn(__fmul_rn(wg, wrt.x), omw), wlu.x);
            const float cww1 = __fadd_rn(__fadd_rn(__fmul_rn(wg, wrt.y), omw), wlu.y);
            const float cu0 = __fadd_rn(__fadd_rn(__fmul_rn(0.95f, wut.x), w0), cww0);
            const float cu1 = __fadd_rn(__fadd_rn(__fmul_rn(0.95f, wut.y), w1), cww1);
            ((float2*)(out + OUT_CWR))[(size_t)m * 64 + l] = make_float2(w0, w1);
            ((float2*)(out + OUT_CWU))[(size_t)m * 64 + l] = make_float2(cu0, cu1);
            const unsigned long long e0u = (((unsigned long long)fenc(cu0)) << 32) | (unsigned)m;
            const unsigned long long e1u = (((unsigned long long)fenc(cu1)) << 32) | (unsigned)m;
            lmin0 = (e0u < lmin0) ? e0u : lmin0;   // min accumulation order-free (exact)
            lmin1 = (e1u < lmin1) ? e1u : lmin1;
        }
    }
    atomicMin(&minenc[2 * l], lmin0);
    atomicMin(&minenc[2 * l + 1], lmin1);
}

// ---------------- K3: global argmin (first-occurrence) ----------------
__global__ void k_argmin(const unsigned long long* __restrict__ minenc,
                         float* __restrict__ mins, unsigned* __restrict__ istar)
{
    __shared__ unsigned long long red[NB];
    const int t = threadIdx.x;
    const unsigned long long e = minenc[t];
    const unsigned enc32 = (unsigned)(e >> 32);
    mins[t] = fdec(enc32);
    red[t] = (((unsigned long long)enc32) << 32) | (unsigned)t;
    __syncthreads();
    for (int s = 64; s > 0; s >>= 1) {
        if (t < s) { const unsigned long long o = red[t + s]; if (o < red[t]) red[t] = o; }
        __syncthreads();
    }
    if (t == 0) {
        const unsigned bstar = (unsigned)(red[0] & 0xFFFFFFFFu);
        istar[0] = (unsigned)(minenc[bstar] & 0xFFFFFFFFu);
    }
}

// -------- K4a: memory = cww @ key (bf16 MFMA) + 128*keep*m (f32) + c_wlu (UNCHANGED) --------
__global__ __launch_bounds__(256, 2) void k_mem(
    const float* __restrict__ mT,
    const float* __restrict__ cwr_t, const float* __restrict__ cwlu_t,
    const float* __restrict__ wgp, const float* __restrict__ mins,
    const unsigned* __restrict__ istar_p, float* __restrict__ out)
{
    __shared__ unsigned short cwwb[128 * 136];   // [s][b] bf16, stride 136
    __shared__ unsigned short keyT[128 * 136];   // [u_local][b] bf16, one u-half
    const int t = threadIdx.x, w = t >> 6, l = t & 63;
    const int sb = blockIdx.x * 128;
    const float wg = sigm(wgp[0]);
    const float omw = __fsub_rn(1.f, wg);
    const int istar = (int)istar_p[0];

    // ---- S1: cww -> bf16 LDS; c_wlu -> global (exact f32 chain) ----
    {
        const int srow = t >> 5;
        const int bc = (t & 31) * 4;
        for (int it = 0; it < 16; ++it) {
            const int s = it * 8 + srow;
            const size_t row = (size_t)(sb + s) * NB + bc;
            const float4 wr = *(const float4*)(cwr_t + row);
            const float4 lu = *(const float4*)(cwlu_t + row);
            const float4 wu = *(const float4*)(out + OUT_CWU + row);
            float4 cw;
            cw.x = __fadd_rn(__fadd_rn(__fmul_rn(wg, wr.x), omw), lu.x);
            cw.y = __fadd_rn(__fadd_rn(__fmul_rn(wg, wr.y), omw), lu.y);
            cw.z = __fadd_rn(__fadd_rn(__fmul_rn(wg, wr.z), omw), lu.z);
            cw.w = __fadd_rn(__fadd_rn(__fmul_rn(wg, wr.w), omw), lu.w);
            ushort4 pk;
            pk.x = f2b(cw.x); pk.y = f2b(cw.y); pk.z = f2b(cw.z); pk.w = f2b(cw.w);
            *(ushort4*)&cwwb[s * 136 + bc] = pk;
            const float4 mb = *(const float4*)(mins + bc);
            float4 wl;
            wl.x = (wu.x <= mb.x) ? 1.f : 0.f;
            wl.y = (wu.y <= mb.y) ? 1.f : 0.f;
            wl.z = (wu.z <= mb.z) ? 1.f : 0.f;
            wl.w = (wu.w <= mb.w) ? 1.f : 0.f;
            *(float4*)(out + OUT_CWLU + row) = wl;
        }
    }

    const int rk = (l >> 4) * 8;
    const int rr = l & 15;

    for (int uh = 0; uh < 2; ++uh) {
        if (uh) __syncthreads();
        // ---- S2: keyT half uh: key[b][u] f32 -> bf16 LDS [u_local][b] ----
        {
            const int br = t >> 5;
            const int ko = (t & 31) * 4;
            for (int it = 0; it < 16; ++it) {
                const int b = it * 8 + br;
                const float4 kv = *(const float4*)(out + OUT_KEY + (size_t)b * NU + uh * 128 + ko);
                keyT[(ko + 0) * 136 + b] = f2b(kv.x);
                keyT[(ko + 1) * 136 + b] = f2b(kv.y);
                keyT[(ko + 2) * 136 + b] = f2b(kv.z);
                keyT[(ko + 3) * 136 + b] = f2b(kv.w);
            }
        }
        __syncthreads();

        // ---- MFMA: wave w -> s-tiles {2w, 2w+1}; 8 u-tiles; K=128 in 4 chunks ----
        floatx4 acc0[8], acc1[8];
        #pragma unroll
        for (int ut = 0; ut < 8; ++ut) {
            acc0[ut] = (floatx4){0.f, 0.f, 0.f, 0.f};
            acc1[ut] = (floatx4){0.f, 0.f, 0.f, 0.f};
        }
        #pragma unroll
        for (int kc = 0; kc < 4; ++kc) {
            const short8v a0 = *(const short8v*)&cwwb[(w * 32 + rr) * 136 + kc * 32 + rk];
            const short8v a1 = *(const short8v*)&cwwb[(w * 32 + 16 + rr) * 136 + kc * 32 + rk];
            #pragma unroll
            for (int ut = 0; ut < 8; ++ut) {
                const short8v bf = *(const short8v*)&keyT[(ut * 16 + rr) * 136 + kc * 32 + rk];
                acc0[ut] = __builtin_amdgcn_mfma_f32_16x16x32_bf16(a0, bf, acc0[ut], 0, 0, 0);
                acc1[ut] = __builtin_amdgcn_mfma_f32_16x16x32_bf16(a1, bf, acc1[ut], 0, 0, 0);
            }
        }

        // ---- epilogue: D + keep*128*m (exact f32) -> OUT_MEM ----
        #pragma unroll
        for (int ut = 0; ut < 8; ++ut) {
            const int gcol = uh * 128 + ut * 16 + rr;
            #pragma unroll
            for (int q = 0; q < 4; ++q) {
                const int grow0 = sb + w * 32 + (l >> 4) * 4 + q;
                const int grow1 = grow0 + 16;
                const float mv0 = mT[(size_t)grow0 * NU + gcol];
                const float mv1 = mT[(size_t)grow1 * NU + gcol];
                const float kf0 = (grow0 == istar) ? 0.f : 128.f;
                const float kf1 = (grow1 == istar) ? 0.f : 128.f;
                out[OUT_MEM + (size_t)grow0 * NU + gcol] = acc0[ut][q] + kf0 * mv0;
                out[OUT_MEM + (size_t)grow1 * NU + gcol] = acc1[ut][q] + kf1 * mv1;
            }
        }
    }
}

// -------- K4b: read = c_wr.T @ m_tm1, register-tiled 8b x 8u, partials in ws --------
template <int USE_PART>
__global__ __launch_bounds__(256) void k_read(
    const float* __restrict__ mT, float* __restrict__ out, float* __restrict__ part)
{
    __shared__ float m_ch[2][8][128];
    __shared__ float cwr_ch[2][8][128];
    const int t = threadIdx.x;
    const int r = blockIdx.x, ri = r >> 1, uh = r & 1;
    const int s0 = ri * 256;
    const int b0 = (t & 15) * 8, u0 = (t >> 4) * 8;
    const int ssl = t >> 5, sul = (t & 31) * 4;

    float4 acc[8][2];
    #pragma unroll
    for (int bi = 0; bi < 8; ++bi) { acc[bi][0] = make_float4(0,0,0,0); acc[bi][1] = make_float4(0,0,0,0); }

    // prefetch chunk 0
    float4 pm = *(const float4*)(mT + (size_t)(s0 + ssl) * NU + uh * 128 + sul);
    float4 pc = *(const float4*)(out + OUT_CWR + (size_t)(s0 + ssl) * NB + sul);

    for (int c = 0; c < 32; ++c) {
        const int buf = c & 1;
        *(float4*)&m_ch[buf][ssl][sul] = pm;
        *(float4*)&cwr_ch[buf][ssl][sul] = pc;
        __syncthreads();
        if (c + 1 < 32) {   // prefetch next chunk (hidden under compute)
            const size_t sn = (size_t)(s0 + (c + 1) * 8 + ssl);
            pm = *(const float4*)(mT + sn * NU + uh * 128 + sul);
            pc = *(const float4*)(out + OUT_CWR + sn * NB + sul);
        }
        #pragma unroll
        for (int sj = 0; sj < 8; ++sj) {
            const float4 ca = *(const float4*)&cwr_ch[buf][sj][b0];
            const float4 cb = *(const float4*)&cwr_ch[buf][sj][b0 + 4];
            const float4 ma = *(const float4*)&m_ch[buf][sj][u0];
            const float4 mb = *(const float4*)&m_ch[buf][sj][u0 + 4];
            const float cwa[8] = {ca.x, ca.y, ca.z, ca.w, cb.x, cb.y, cb.z, cb.w};
            #pragma unroll
            for (int bi = 0; bi < 8; ++bi) {
                acc[bi][0].x += cwa[bi] * ma.x; acc[bi][0].y += cwa[bi] * ma.y;
                acc[bi][0].z += cwa[bi] * ma.z; acc[bi][0].w += cwa[bi] * ma.w;
                acc[bi][1].x += cwa[bi] * mb.x; acc[bi][1].y += cwa[bi] * mb.y;
                acc[bi][1].z += cwa[bi] * mb.z; acc[bi][1].w += cwa[bi] * mb.w;
            }
        }
    }

    if (USE_PART) {
        float* dst = part + (size_t)r * (128 * 128);
        #pragma unroll
        for (int bi = 0; bi < 8; ++bi) {
            *(float4*)(dst + (size_t)(b0 + bi) * 128 + u0) = acc[bi][0];
            *(float4*)(dst + (size_t)(b0 + bi) * 128 + u0 + 4) = acc[bi][1];
        }
    } else {
        #pragma unroll
        for (int bi = 0; bi < 8; ++bi) {
            const float v[8] = {acc[bi][0].x, acc[bi][0].y, acc[bi][0].z, acc[bi][0].w,
                                acc[bi][1].x, acc[bi][1].y, acc[bi][1].z, acc[bi][1].w};
            #pragma unroll
            for (int q = 0; q < 8; ++q)
                atomicAdd(out + OUT_READ + (size_t)(b0 + bi) * NU + uh * 128 + u0 + q, v[q]);
        }
    }
}

// ---------------- K5: deterministic read reduction ----------------
__global__ __launch_bounds__(256) void k_redread(const float* __restrict__ part,
                                                 float* __restrict__ out)
{
    const int b = blockIdx.x, u = threadIdx.x;
    const int uh = u >> 7, ul = u & 127;
    float s = 0.f;
    #pragma unroll 4
    for (int ri = 0; ri < 256; ++ri)
        s += part[((size_t)(ri * 2 + uh) * 128 + b) * 128 + ul];
    out[OUT_READ + b * NU + u] = s;
}

extern "C" void kernel_launch(void* const* d_in, const int* in_sizes, int n_in,
                              void* d_out, int out_size, void* d_ws, size_t ws_size,
                              hipStream_t stream)
{
    const float* inputs    = (const float*)d_in[0];
    const float* r_tm1     = (const float*)d_in[1];
    const float* m_tm1     = (const float*)d_in[2];
    const float* c_wu_tm1  = (const float*)d_in[3];
    const float* c_wlu_tm1 = (const float*)d_in[4];
    const float* c_wr_tm1  = (const float*)d_in[5];
    const float* h_tm1     = (const float*)d_in[6];
    const float* cc_tm1    = (const float*)d_in[7];
    const float* Wk        = (const float*)d_in[8];
    const float* Wr        = (const float*)d_in[9];
    const float* bias      = (const float*)d_in[10];
    const float* wgate     = (const float*)d_in[11];
    float* out = (float*)d_out;
    char* ws = (char*)d_ws;

    float* klnT = (float*)(ws + WS_KLNT);
    unsigned long long* minenc = (unsigned long long*)(ws + WS_MINENC);
    float* mins = (float*)(ws + WS_MINS);
    unsigned* istar = (unsigned*)(ws + WS_ISTAR);
    float* part = (float*)(ws + WS_PART);
    const bool use_part = ws_size >= WS_PART + (size_t)512 * 128 * 128 * 4;

    hipLaunchKernelGGL(k_lstm, dim3(128), dim3(256), 0, stream,
                       inputs, r_tm1, h_tm1, cc_tm1, Wk, Wr, bias, out, klnT, minenc);
    hipLaunchKernelGGL(k_dot, dim3(512), dim3(256), 0, stream,
                       m_tm1, klnT, c_wr_tm1, c_wlu_tm1, c_wu_tm1, wgate, out, minenc);
    hipLaunchKernelGGL(k_argmin, dim3(1), dim3(128), 0, stream, minenc, mins, istar);
    hipLaunchKernelGGL(k_mem, dim3(512), dim3(256), 0, stream,
                       m_tm1, c_wr_tm1, c_wlu_tm1, wgate, mins, istar, out);
    if (use_part) {
        hipLaunchKernelGGL((k_read<1>), dim3(512), dim3(256), 0, stream, m_tm1, out, part);
        hipLaunchKernelGGL(k_redread, dim3(128), dim3(256), 0, stream, part, out);
    } else {
        hipLaunchKernelGGL((k_read<0>), dim3(512), dim3(256), 0, stream, m_tm1, out, part);
    }
}

// Round 10
// 405.026 us; speedup vs baseline: 1.0991x; 1.0991x over previous
//
#include <hip/hip_runtime.h>
#include <hip/hip_bf16.h>
#include <math.h>

#define NM 65536
#define NB 128
#define NU 256
#define ND 512

// ---- output layout (flat f32, reference return order) ----
constexpr size_t OUT_READ = 0;                      // [B,U]    32768
constexpr size_t OUT_MEM  = 32768;                  // [M,U]    16777216
constexpr size_t OUT_CWU  = OUT_MEM + 16777216;     // [M,B]    8388608
constexpr size_t OUT_CWLU = OUT_CWU + 8388608;      // [M,B]
constexpr size_t OUT_CWR  = OUT_CWLU + 8388608;     // [M,B]
constexpr size_t OUT_KEY  = OUT_CWR + 8388608;      // [B,U]
constexpr size_t OUT_CC   = OUT_KEY + 32768;        // [B,U]

// ---- ws layout (bytes) ----
constexpr size_t WS_KLNT   = 0;        // 32768 f32 (klnT[u][b])
constexpr size_t WS_MINENC = 131072;   // 128 u64
constexpr size_t WS_MINS   = 132096;   // 128 f32
constexpr size_t WS_ISTAR  = 132608;   // 1 u32
constexpr size_t WS_PART   = 135168;   // 512 * 16384 f32 read-partials (32 MB)

typedef __attribute__((ext_vector_type(8))) short short8v;   // 8 bf16 (4 VGPRs)
typedef __attribute__((ext_vector_type(4))) float floatx4;

__device__ __forceinline__ unsigned fenc(float x) {
    unsigned u = __float_as_uint(x);
    return (u & 0x80000000u) ? ~u : (u | 0x80000000u);
}
__device__ __forceinline__ float fdec(unsigned e) {
    unsigned u = (e & 0x80000000u) ? (e ^ 0x80000000u) : ~e;
    return __uint_as_float(u);
}
__device__ __forceinline__ float sigm(float x) { return 1.0f / (1.0f + expf(-x)); }
__device__ __forceinline__ unsigned short f2b(float f) {
    __hip_bfloat16 h = __float2bfloat16(f);      // RNE
    return *reinterpret_cast<unsigned short*>(&h);
}

// ---------------- K1: LSTM controller + normalized keys (UNCHANGED, numerics anchor) ----------------
__global__ __launch_bounds__(256) void k_lstm(
    const float* __restrict__ xin_g, const float* __restrict__ r_tm1,
    const float* __restrict__ h_tm1, const float* __restrict__ cc_tm1,
    const float* __restrict__ Wk, const float* __restrict__ Wr,
    const float* __restrict__ bias, float* __restrict__ out,
    float* __restrict__ klnT, unsigned long long* __restrict__ minenc)
{
    const int b = blockIdx.x, t = threadIdx.x;
    __shared__ float xin[ND + NU];
    __shared__ float hh[NU];
    __shared__ float red[NU];
    for (int k = t; k < ND; k += 256) xin[k] = xin_g[b * ND + k];
    xin[ND + t] = r_tm1[b * NU + t];
    hh[t] = h_tm1[b * NU + t];
    out[OUT_READ + b * NU + t] = 0.f;              // zero read region each launch
    if (b == 0 && t < NB) minenc[t] = ~0ULL;       // init argmin atomics
    __syncthreads();

    float zi = bias[t], zf = bias[NU + t], zc = bias[2 * NU + t], zo = bias[3 * NU + t];
    #pragma unroll 4
    for (int k = 0; k < ND + NU; ++k) {
        const float x = xin[k];
        const float* w = Wk + (size_t)k * (4 * NU);
        zi += x * w[t]; zf += x * w[NU + t]; zc += x * w[2 * NU + t]; zo += x * w[3 * NU + t];
    }
    #pragma unroll 4
    for (int k = 0; k < NU; ++k) {
        const float x = hh[k];
        const float* w = Wr + (size_t)k * (4 * NU);
        zi += x * w[t]; zf += x * w[NU + t]; zc += x * w[2 * NU + t]; zo += x * w[3 * NU + t];
    }
    const float gi = sigm(zi), gf = sigm(zf), gc = tanhf(zc), go = sigm(zo);
    const float cold = cc_tm1[b * NU + t];
    const float cn = __fadd_rn(__fmul_rn(gf, cold), __fmul_rn(gi, gc));
    const float hn = __fmul_rn(go, tanhf(cn));
    out[OUT_KEY + b * NU + t] = hn;
    out[OUT_CC + b * NU + t] = cn;
    red[t] = hn * hn;
    __syncthreads();
    for (int s = 128; s > 0; s >>= 1) { if (t < s) red[t] += red[t + s]; __syncthreads(); }
    const float nrm = sqrtf(fmaxf(red[0], 1e-12f));
    klnT[t * NB + b] = hn / nrm;   // transposed [u][b]
}

// ------------- K2: fused norm + cosine GEMM + batch-softmax + usage + min -------------
// EXACT R4/R8 kernel (best measured: 181 us; bit-identical numerics path).
__global__ __launch_bounds__(256, 2) void k_dot(
    const float* __restrict__ mT, const float* __restrict__ klnT,
    const float* __restrict__ cwr_t, const float* __restrict__ cwlu_t,
    const float* __restrict__ cwu_t, const float* __restrict__ wgp,
    float* __restrict__ out, unsigned long long* __restrict__ minenc)
{
    __shared__ float smem[16384];      // 64 KB: stage tiles (32 KB), later dot tile [128][128]
    __shared__ float rn_s[128];
    const int t = threadIdx.x, w = t >> 6, l = t & 63;
    const int tx = t & 15, ty = t >> 4;
    const int b0 = tx * 8, s0 = ty * 8;
    const int sb = blockIdx.x * 128;

    // ---- phase 0: row norms (bit-identical: lane-l float4 + xor tree) ----
    #pragma unroll 4
    for (int i = 0; i < 32; ++i) {
        const int s = w * 32 + i;
        const float4 mv = *(const float4*)(mT + (size_t)(sb + s) * NU + l * 4);
        float ss = mv.x * mv.x + mv.y * mv.y + mv.z * mv.z + mv.w * mv.w;
        #pragma unroll
        for (int d = 1; d < 64; d <<= 1) ss += __shfl_xor(ss, d);
        if (l == 0) rn_s[s] = sqrtf(fmaxf(ss, 1e-12f));   // wave-private write/read
    }

    // ---- phase 1: GEMM dot[s][b] = sum_u m[s][u] * kln[u][b] ----
    const int sl = t & 127, ug = t >> 7;       // ms stage: slot sl, u-halves
    const int ku_ = t >> 4, kb = (t & 15) * 4; // kl stage

    float acc[8][8];
    #pragma unroll
    for (int i = 0; i < 8; ++i)
        #pragma unroll
        for (int j = 0; j < 8; ++j) acc[i][j] = 0.f;

    float4 gm[2], gk[2];
    #pragma unroll
    for (int i = 0; i < 2; ++i) {
        gm[i] = *(const float4*)(mT + (size_t)(sb + sl) * NU + (ug + 2 * i) * 4);
        gk[i] = *(const float4*)(klnT + (size_t)ku_ * NB + kb + i * 64);
    }
    for (int c = 0; c < 16; ++c) {
        const int mo = (c & 1) * 2048;          // ms buffer offset
        const int ko = 4096 + (c & 1) * 2048;   // kl buffer offset
        #pragma unroll
        for (int i = 0; i < 2; ++i) {
            const int uo = (ug + 2 * i) * 4;
            smem[mo + (uo + 0) * 128 + sl] = gm[i].x;
            smem[mo + (uo + 1) * 128 + sl] = gm[i].y;
            smem[mo + (uo + 2) * 128 + sl] = gm[i].z;
            smem[mo + (uo + 3) * 128 + sl] = gm[i].w;
            *(float4*)&smem[ko + ku_ * 128 + kb + i * 64] = gk[i];
        }
        __syncthreads();
        if (c < 15) {   // prefetch next chunk into registers (overlaps compute)
            const int uc = (c + 1) * 16;
            #pragma unroll
            for (int i = 0; i < 2; ++i) {
                gm[i] = *(const float4*)(mT + (size_t)(sb + sl) * NU + uc + (ug + 2 * i) * 4);
                gk[i] = *(const float4*)(klnT + (size_t)(uc + ku_) * NB + kb + i * 64);
            }
        }
        #pragma unroll 4
        for (int u = 0; u < 16; ++u) {
            const float4 sv0 = *(const float4*)&smem[mo + u * 128 + s0];
            const float4 sv1 = *(const float4*)&smem[mo + u * 128 + s0 + 4];
            const float4 kv0 = *(const float4*)&smem[ko + u * 128 + b0];
            const float4 kv1 = *(const float4*)&smem[ko + u * 128 + b0 + 4];
            const float sv[8] = {sv0.x, sv0.y, sv0.z, sv0.w, sv1.x, sv1.y, sv1.z, sv1.w};
            const float kv[8] = {kv0.x, kv0.y, kv0.z, kv0.w, kv1.x, kv1.y, kv1.z, kv1.w};
            #pragma unroll
            for (int i = 0; i < 8; ++i)
                #pragma unroll
                for (int j = 0; j < 8; ++j)
                    acc[i][j] += sv[i] * kv[j];   // single fmac chain ascending u per (s,b)
        }
        __syncthreads();
    }

    // ---- phase 2: spill dot tile to LDS (aliases stage buffers; barrier-protected) ----
    #pragma unroll
    for (int i = 0; i < 8; ++i) {
        *(float4*)&smem[(s0 + i) * 128 + b0]     = make_float4(acc[i][0], acc[i][1], acc[i][2], acc[i][3]);
        *(float4*)&smem[(s0 + i) * 128 + b0 + 4] = make_float4(acc[i][4], acc[i][5], acc[i][6], acc[i][7]);
    }
    __syncthreads();

    // ---- phase 3: per-slot softmax + usage + min (exact epilogue, lane = b-pair) ----
    const float wg = sigm(wgp[0]);
    const float omw = __fsub_rn(1.f, wg);
    unsigned long long lmin0 = ~0ULL, lmin1 = ~0ULL;
    #pragma unroll 2
    for (int i = 0; i < 32; ++i) {
        const int s = w * 32 + i;
        const int m = sb + s;
        const float2 dv = *(const float2*)&smem[s * 128 + 2 * l];
        const float rnv = rn_s[s];
        const float2 wrt = ((const float2*)(cwr_t + (size_t)m * NB))[l];
        const float2 wlu = ((const float2*)(cwlu_t + (size_t)m * NB))[l];
        const float2 wut = ((const float2*)(cwu_t + (size_t)m * NB))[l];
        const float c0 = dv.x / rnv, c1 = dv.y / rnv;
        float mx = fmaxf(c0, c1);
        #pragma unroll
        for (int d = 1; d < 64; d <<= 1) mx = fmaxf(mx, __shfl_xor(mx, d));
        const float e0 = expf(c0 - mx), e1 = expf(c1 - mx);
        float sm = e0 + e1;
        #pragma unroll
        for (int d = 1; d < 64; d <<= 1) sm += __shfl_xor(sm, d);
        const float w0 = e0 / sm, w1 = e1 / sm;
        const float cww0 = __fadd_rn(__fadd_rn(__fmul_rn(wg, wrt.x), omw), wlu.x);
        const float cww1 = __fadd_rn(__fadd_rn(__fmul_rn(wg, wrt.y), omw), wlu.y);
        const float cu0 = __fadd_rn(__fadd_rn(__fmul_rn(0.95f, wut.x), w0), cww0);
        const float cu1 = __fadd_rn(__fadd_rn(__fmul_rn(0.95f, wut.y), w1), cww1);
        ((float2*)(out + OUT_CWR))[(size_t)m * 64 + l] = make_float2(w0, w1);
        ((float2*)(out + OUT_CWU))[(size_t)m * 64 + l] = make_float2(cu0, cu1);
        const unsigned long long e0u = (((unsigned long long)fenc(cu0)) << 32) | (unsigned)m;
        const unsigned long long e1u = (((unsigned long long)fenc(cu1)) << 32) | (unsigned)m;
        lmin0 = (e0u < lmin0) ? e0u : lmin0;
        lmin1 = (e1u < lmin1) ? e1u : lmin1;
    }
    atomicMin(&minenc[2 * l], lmin0);
    atomicMin(&minenc[2 * l + 1], lmin1);
}

// ---------------- K3: global argmin (first-occurrence) ----------------
__global__ void k_argmin(const unsigned long long* __restrict__ minenc,
                         float* __restrict__ mins, unsigned* __restrict__ istar)
{
    __shared__ unsigned long long red[NB];
    const int t = threadIdx.x;
    const unsigned long long e = minenc[t];
    const unsigned enc32 = (unsigned)(e >> 32);
    mins[t] = fdec(enc32);
    red[t] = (((unsigned long long)enc32) << 32) | (unsigned)t;
    __syncthreads();
    for (int s = 64; s > 0; s >>= 1) {
        if (t < s) { const unsigned long long o = red[t + s]; if (o < red[t]) red[t] = o; }
        __syncthreads();
    }
    if (t == 0) {
        const unsigned bstar = (unsigned)(red[0] & 0xFFFFFFFFu);
        istar[0] = (unsigned)(minenc[bstar] & 0xFFFFFFFFu);
    }
}

// -------- K4a: memory = cww @ key (bf16 MFMA) + 128*keep*m (f32) + c_wlu (UNCHANGED R8) --------
__global__ __launch_bounds__(256, 2) void k_mem(
    const float* __restrict__ mT,
    const float* __restrict__ cwr_t, const float* __restrict__ cwlu_t,
    const float* __restrict__ wgp, const float* __restrict__ mins,
    const unsigned* __restrict__ istar_p, float* __restrict__ out)
{
    __shared__ unsigned short cwwb[128 * 136];   // [s][b] bf16, stride 136
    __shared__ unsigned short keyT[128 * 136];   // [u_local][b] bf16, one u-half
    const int t = threadIdx.x, w = t >> 6, l = t & 63;
    const int sb = blockIdx.x * 128;
    const float wg = sigm(wgp[0]);
    const float omw = __fsub_rn(1.f, wg);
    const int istar = (int)istar_p[0];

    // ---- S1: cww -> bf16 LDS; c_wlu -> global (exact f32 chain) ----
    {
        const int srow = t >> 5;
        const int bc = (t & 31) * 4;
        for (int it = 0; it < 16; ++it) {
            const int s = it * 8 + srow;
            const size_t row = (size_t)(sb + s) * NB + bc;
            const float4 wr = *(const float4*)(cwr_t + row);
            const float4 lu = *(const float4*)(cwlu_t + row);
            const float4 wu = *(const float4*)(out + OUT_CWU + row);
            float4 cw;
            cw.x = __fadd_rn(__fadd_rn(__fmul_rn(wg, wr.x), omw), lu.x);
            cw.y = __fadd_rn(__fadd_rn(__fmul_rn(wg, wr.y), omw), lu.y);
            cw.z = __fadd_rn(__fadd_rn(__fmul_rn(wg, wr.z), omw), lu.z);
            cw.w = __fadd_rn(__fadd_rn(__fmul_rn(wg, wr.w), omw), lu.w);
            ushort4 pk;
            pk.x = f2b(cw.x); pk.y = f2b(cw.y); pk.z = f2b(cw.z); pk.w = f2b(cw.w);
            *(ushort4*)&cwwb[s * 136 + bc] = pk;
            const float4 mb = *(const float4*)(mins + bc);
            float4 wl;
            wl.x = (wu.x <= mb.x) ? 1.f : 0.f;
            wl.y = (wu.y <= mb.y) ? 1.f : 0.f;
            wl.z = (wu.z <= mb.z) ? 1.f : 0.f;
            wl.w = (wu.w <= mb.w) ? 1.f : 0.f;
            *(float4*)(out + OUT_CWLU + row) = wl;
        }
    }

    const int rk = (l >> 4) * 8;
    const int rr = l & 15;

    for (int uh = 0; uh < 2; ++uh) {
        if (uh) __syncthreads();
        // ---- S2: keyT half uh: key[b][u] f32 -> bf16 LDS [u_local][b] ----
        {
            const int br = t >> 5;
            const int ko = (t & 31) * 4;
            for (int it = 0; it < 16; ++it) {
                const int b = it * 8 + br;
                const float4 kv = *(const float4*)(out + OUT_KEY + (size_t)b * NU + uh * 128 + ko);
                keyT[(ko + 0) * 136 + b] = f2b(kv.x);
                keyT[(ko + 1) * 136 + b] = f2b(kv.y);
                keyT[(ko + 2) * 136 + b] = f2b(kv.z);
                keyT[(ko + 3) * 136 + b] = f2b(kv.w);
            }
        }
        __syncthreads();

        // ---- MFMA: wave w -> s-tiles {2w, 2w+1}; 8 u-tiles; K=128 in 4 chunks ----
        floatx4 acc0[8], acc1[8];
        #pragma unroll
        for (int ut = 0; ut < 8; ++ut) {
            acc0[ut] = (floatx4){0.f, 0.f, 0.f, 0.f};
            acc1[ut] = (floatx4){0.f, 0.f, 0.f, 0.f};
        }
        #pragma unroll
        for (int kc = 0; kc < 4; ++kc) {
            const short8v a0 = *(const short8v*)&cwwb[(w * 32 + rr) * 136 + kc * 32 + rk];
            const short8v a1 = *(const short8v*)&cwwb[(w * 32 + 16 + rr) * 136 + kc * 32 + rk];
            #pragma unroll
            for (int ut = 0; ut < 8; ++ut) {
                const short8v bf = *(const short8v*)&keyT[(ut * 16 + rr) * 136 + kc * 32 + rk];
                acc0[ut] = __builtin_amdgcn_mfma_f32_16x16x32_bf16(a0, bf, acc0[ut], 0, 0, 0);
                acc1[ut] = __builtin_amdgcn_mfma_f32_16x16x32_bf16(a1, bf, acc1[ut], 0, 0, 0);
            }
        }

        // ---- epilogue: D + keep*128*m (exact f32) -> OUT_MEM ----
        #pragma unroll
        for (int ut = 0; ut < 8; ++ut) {
            const int gcol = uh * 128 + ut * 16 + rr;
            #pragma unroll
            for (int q = 0; q < 4; ++q) {
                const int grow0 = sb + w * 32 + (l >> 4) * 4 + q;
                const int grow1 = grow0 + 16;
                const float mv0 = mT[(size_t)grow0 * NU + gcol];
                const float mv1 = mT[(size_t)grow1 * NU + gcol];
                const float kf0 = (grow0 == istar) ? 0.f : 128.f;
                const float kf1 = (grow1 == istar) ? 0.f : 128.f;
                out[OUT_MEM + (size_t)grow0 * NU + gcol] = acc0[ut][q] + kf0 * mv0;
                out[OUT_MEM + (size_t)grow1 * NU + gcol] = acc1[ut][q] + kf1 * mv1;
            }
        }
    }
}

// -------- K4b v2: read = c_wr.T @ m_tm1 via bf16 MFMA, fragments direct from global --------
// D[b][u] tiles: A[b][k=m] = cwr[m][b] (strided dwords, k via imm offsets i*NB);
// B[k=m][col=u] = m[m][u] (i*NU). Lane maps identical to the R8-verified k_mem.
// No LDS, no barriers; 8 K-steps of 32 slots; acc 64 VGPR.
template <int USE_PART>
__global__ __launch_bounds__(256) void k_read(
    const float* __restrict__ mT, float* __restrict__ out, float* __restrict__ part)
{
    const int t = threadIdx.x, w = t >> 6, l = t & 63;
    const int r = blockIdx.x, ri = r >> 1, uh = r & 1;
    const int rk = (l >> 4) * 8, rr = l & 15;
    const float* cwr = out + OUT_CWR;

    floatx4 acc[2][8];
    #pragma unroll
    for (int bt = 0; bt < 2; ++bt)
        #pragma unroll
        for (int ut = 0; ut < 8; ++ut) acc[bt][ut] = (floatx4){0.f, 0.f, 0.f, 0.f};

    for (int c = 0; c < 8; ++c) {
        const size_t m0 = (size_t)(ri * 256 + c * 32 + rk);
        short8v a[2];
        #pragma unroll
        for (int bt = 0; bt < 2; ++bt) {
            const float* ap = cwr + m0 * NB + w * 32 + bt * 16 + rr;
            #pragma unroll
            for (int i = 0; i < 8; ++i) a[bt][i] = (short)f2b(ap[i * NB]);
        }
        short8v bf[8];
        #pragma unroll
        for (int ut = 0; ut < 8; ++ut) {
            const float* bp = mT + m0 * NU + uh * 128 + ut * 16 + rr;
            #pragma unroll
            for (int i = 0; i < 8; ++i) bf[ut][i] = (short)f2b(bp[i * NU]);
        }
        #pragma unroll
        for (int bt = 0; bt < 2; ++bt)
            #pragma unroll
            for (int ut = 0; ut < 8; ++ut)
                acc[bt][ut] = __builtin_amdgcn_mfma_f32_16x16x32_bf16(a[bt], bf[ut], acc[bt][ut], 0, 0, 0);
    }

    // D mapping (m89-verified): col = l&15, row = (l>>4)*4 + q
    if (USE_PART) {
        float* dst = part + (size_t)r * (128 * 128);
        #pragma unroll
        for (int bt = 0; bt < 2; ++bt)
            #pragma unroll
            for (int ut = 0; ut < 8; ++ut)
                #pragma unroll
                for (int q = 0; q < 4; ++q)
                    dst[(size_t)(w * 32 + bt * 16 + (l >> 4) * 4 + q) * 128 + ut * 16 + rr] = acc[bt][ut][q];
    } else {
        #pragma unroll
        for (int bt = 0; bt < 2; ++bt)
            #pragma unroll
            for (int ut = 0; ut < 8; ++ut)
                #pragma unroll
                for (int q = 0; q < 4; ++q)
                    atomicAdd(out + OUT_READ + (size_t)(w * 32 + bt * 16 + (l >> 4) * 4 + q) * NU
                                  + uh * 128 + ut * 16 + rr, acc[bt][ut][q]);
    }
}

// ---------------- K5: deterministic read reduction ----------------
__global__ __launch_bounds__(256) void k_redread(const float* __restrict__ part,
                                                 float* __restrict__ out)
{
    const int b = blockIdx.x, u = threadIdx.x;
    const int uh = u >> 7, ul = u & 127;
    float s = 0.f;
    #pragma unroll 4
    for (int ri = 0; ri < 256; ++ri)
        s += part[((size_t)(ri * 2 + uh) * 128 + b) * 128 + ul];
    out[OUT_READ + b * NU + u] = s;
}

extern "C" void kernel_launch(void* const* d_in, const int* in_sizes, int n_in,
                              void* d_out, int out_size, void* d_ws, size_t ws_size,
                              hipStream_t stream)
{
    const float* inputs    = (const float*)d_in[0];
    const float* r_tm1     = (const float*)d_in[1];
    const float* m_tm1     = (const float*)d_in[2];
    const float* c_wu_tm1  = (const float*)d_in[3];
    const float* c_wlu_tm1 = (const float*)d_in[4];
    const float* c_wr_tm1  = (const float*)d_in[5];
    const float* h_tm1     = (const float*)d_in[6];
    const float* cc_tm1    = (const float*)d_in[7];
    const float* Wk        = (const float*)d_in[8];
    const float* Wr        = (const float*)d_in[9];
    const float* bias      = (const float*)d_in[10];
    const float* wgate     = (const float*)d_in[11];
    float* out = (float*)d_out;
    char* ws = (char*)d_ws;

    float* klnT = (float*)(ws + WS_KLNT);
    unsigned long long* minenc = (unsigned long long*)(ws + WS_MINENC);
    float* mins = (float*)(ws + WS_MINS);
    unsigned* istar = (unsigned*)(ws + WS_ISTAR);
    float* part = (float*)(ws + WS_PART);
    const bool use_part = ws_size >= WS_PART + (size_t)512 * 128 * 128 * 4;

    hipLaunchKernelGGL(k_lstm, dim3(128), dim3(256), 0, stream,
                       inputs, r_tm1, h_tm1, cc_tm1, Wk, Wr, bias, out, klnT, minenc);
    hipLaunchKernelGGL(k_dot, dim3(512), dim3(256), 0, stream,
                       m_tm1, klnT, c_wr_tm1, c_wlu_tm1, c_wu_tm1, wgate, out, minenc);
    hipLaunchKernelGGL(k_argmin, dim3(1), dim3(128), 0, stream, minenc, mins, istar);
    hipLaunchKernelGGL(k_mem, dim3(512), dim3(256), 0, stream,
                       m_tm1, c_wr_tm1, c_wlu_tm1, wgate, mins, istar, out);
    if (use_part) {
        hipLaunchKernelGGL((k_read<1>), dim3(512), dim3(256), 0, stream, m_tm1, out, part);
        hipLaunchKernelGGL(k_redread, dim3(128), dim3(256), 0, stream, part, out);
    } else {
        hipLaunchKernelGGL((k_read<0>), dim3(512), dim3(256), 0, stream, m_tm1, out, part);
    }
}

// Round 11
// 401.928 us; speedup vs baseline: 1.1076x; 1.0077x over previous
//
#include <hip/hip_runtime.h>
#include <hip/hip_bf16.h>
#include <math.h>

#define NM 65536
#define NB 128
#define NU 256
#define ND 512

// ---- output layout (flat f32, reference return order) ----
constexpr size_t OUT_READ = 0;                      // [B,U]    32768
constexpr size_t OUT_MEM  = 32768;                  // [M,U]    16777216
constexpr size_t OUT_CWU  = OUT_MEM + 16777216;     // [M,B]    8388608
constexpr size_t OUT_CWLU = OUT_CWU + 8388608;      // [M,B]
constexpr size_t OUT_CWR  = OUT_CWLU + 8388608;     // [M,B]
constexpr size_t OUT_KEY  = OUT_CWR + 8388608;      // [B,U]
constexpr size_t OUT_CC   = OUT_KEY + 32768;        // [B,U]

// ---- ws layout (bytes) ----
constexpr size_t WS_KLNT   = 0;        // 32768 f32 (klnT[u][b])
constexpr size_t WS_MINENC = 131072;   // 128 u64
constexpr size_t WS_MINS   = 132096;   // 128 f32
constexpr size_t WS_ISTAR  = 132608;   // 1 u32
constexpr size_t WS_PART   = 135168;   // 512 * 16384 f32 read-partials (32 MB)

typedef __attribute__((ext_vector_type(8))) short short8v;   // 8 bf16 (4 VGPRs)
typedef __attribute__((ext_vector_type(4))) float floatx4;

__device__ __forceinline__ unsigned fenc(float x) {
    unsigned u = __float_as_uint(x);
    return (u & 0x80000000u) ? ~u : (u | 0x80000000u);
}
__device__ __forceinline__ float fdec(unsigned e) {
    unsigned u = (e & 0x80000000u) ? (e ^ 0x80000000u) : ~e;
    return __uint_as_float(u);
}
__device__ __forceinline__ float sigm(float x) { return 1.0f / (1.0f + expf(-x)); }
__device__ __forceinline__ unsigned short f2b(float f) {
    __hip_bfloat16 h = __float2bfloat16(f);      // RNE
    return *reinterpret_cast<unsigned short*>(&h);
}

// ---------------- K1: LSTM controller + normalized keys (UNCHANGED, numerics anchor) ----------------
__global__ __launch_bounds__(256) void k_lstm(
    const float* __restrict__ xin_g, const float* __restrict__ r_tm1,
    const float* __restrict__ h_tm1, const float* __restrict__ cc_tm1,
    const float* __restrict__ Wk, const float* __restrict__ Wr,
    const float* __restrict__ bias, float* __restrict__ out,
    float* __restrict__ klnT, unsigned long long* __restrict__ minenc)
{
    const int b = blockIdx.x, t = threadIdx.x;
    __shared__ float xin[ND + NU];
    __shared__ float hh[NU];
    __shared__ float red[NU];
    for (int k = t; k < ND; k += 256) xin[k] = xin_g[b * ND + k];
    xin[ND + t] = r_tm1[b * NU + t];
    hh[t] = h_tm1[b * NU + t];
    out[OUT_READ + b * NU + t] = 0.f;              // zero read region each launch
    if (b == 0 && t < NB) minenc[t] = ~0ULL;       // init argmin atomics
    __syncthreads();

    float zi = bias[t], zf = bias[NU + t], zc = bias[2 * NU + t], zo = bias[3 * NU + t];
    #pragma unroll 4
    for (int k = 0; k < ND + NU; ++k) {
        const float x = xin[k];
        const float* w = Wk + (size_t)k * (4 * NU);
        zi += x * w[t]; zf += x * w[NU + t]; zc += x * w[2 * NU + t]; zo += x * w[3 * NU + t];
    }
    #pragma unroll 4
    for (int k = 0; k < NU; ++k) {
        const float x = hh[k];
        const float* w = Wr + (size_t)k * (4 * NU);
        zi += x * w[t]; zf += x * w[NU + t]; zc += x * w[2 * NU + t]; zo += x * w[3 * NU + t];
    }
    const float gi = sigm(zi), gf = sigm(zf), gc = tanhf(zc), go = sigm(zo);
    const float cold = cc_tm1[b * NU + t];
    const float cn = __fadd_rn(__fmul_rn(gf, cold), __fmul_rn(gi, gc));
    const float hn = __fmul_rn(go, tanhf(cn));
    out[OUT_KEY + b * NU + t] = hn;
    out[OUT_CC + b * NU + t] = cn;
    red[t] = hn * hn;
    __syncthreads();
    for (int s = 128; s > 0; s >>= 1) { if (t < s) red[t] += red[t + s]; __syncthreads(); }
    const float nrm = sqrtf(fmaxf(red[0], 1e-12f));
    klnT[t * NB + b] = hn / nrm;   // transposed [u][b]
}

// ------------- K2: fused norm + cosine GEMM + batch-softmax + usage + min -------------
// R4/R8 structure; ONLY change: lane b-columns split as {tx*4..+3} U {64+tx*4..+3}
// so kv LDS reads are 256 consecutive bytes per wave (2-way wrap = conflict-free,
// was 4-way at stride 32B). Thread<->b reassignment only; every (s,b) FMA chain
// is the same ascending-u sequence -> bit-identical outputs.
__global__ __launch_bounds__(256, 2) void k_dot(
    const float* __restrict__ mT, const float* __restrict__ klnT,
    const float* __restrict__ cwr_t, const float* __restrict__ cwlu_t,
    const float* __restrict__ cwu_t, const float* __restrict__ wgp,
    float* __restrict__ out, unsigned long long* __restrict__ minenc)
{
    __shared__ float smem[16384];      // 64 KB: stage tiles (32 KB), later dot tile [128][128]
    __shared__ float rn_s[128];
    const int t = threadIdx.x, w = t >> 6, l = t & 63;
    const int tx = t & 15, ty = t >> 4;
    const int b0a = tx * 4, b0b = 64 + tx * 4;   // split b-columns (conflict-free kv reads)
    const int s0 = ty * 8;
    const int sb = blockIdx.x * 128;

    // ---- phase 0: row norms (bit-identical: lane-l float4 + xor tree) ----
    #pragma unroll 4
    for (int i = 0; i < 32; ++i) {
        const int s = w * 32 + i;
        const float4 mv = *(const float4*)(mT + (size_t)(sb + s) * NU + l * 4);
        float ss = mv.x * mv.x + mv.y * mv.y + mv.z * mv.z + mv.w * mv.w;
        #pragma unroll
        for (int d = 1; d < 64; d <<= 1) ss += __shfl_xor(ss, d);
        if (l == 0) rn_s[s] = sqrtf(fmaxf(ss, 1e-12f));   // wave-private write/read
    }

    // ---- phase 1: GEMM dot[s][b] = sum_u m[s][u] * kln[u][b] ----
    const int sl = t & 127, ug = t >> 7;       // ms stage: slot sl, u-halves
    const int ku_ = t >> 4, kb = (t & 15) * 4; // kl stage

    float acc[8][8];
    #pragma unroll
    for (int i = 0; i < 8; ++i)
        #pragma unroll
        for (int j = 0; j < 8; ++j) acc[i][j] = 0.f;

    float4 gm[2], gk[2];
    #pragma unroll
    for (int i = 0; i < 2; ++i) {
        gm[i] = *(const float4*)(mT + (size_t)(sb + sl) * NU + (ug + 2 * i) * 4);
        gk[i] = *(const float4*)(klnT + (size_t)ku_ * NB + kb + i * 64);
    }
    for (int c = 0; c < 16; ++c) {
        const int mo = (c & 1) * 2048;          // ms buffer offset
        const int ko = 4096 + (c & 1) * 2048;   // kl buffer offset
        #pragma unroll
        for (int i = 0; i < 2; ++i) {
            const int uo = (ug + 2 * i) * 4;
            smem[mo + (uo + 0) * 128 + sl] = gm[i].x;
            smem[mo + (uo + 1) * 128 + sl] = gm[i].y;
            smem[mo + (uo + 2) * 128 + sl] = gm[i].z;
            smem[mo + (uo + 3) * 128 + sl] = gm[i].w;
            *(float4*)&smem[ko + ku_ * 128 + kb + i * 64] = gk[i];
        }
        __syncthreads();
        if (c < 15) {   // prefetch next chunk into registers (overlaps compute)
            const int uc = (c + 1) * 16;
            #pragma unroll
            for (int i = 0; i < 2; ++i) {
                gm[i] = *(const float4*)(mT + (size_t)(sb + sl) * NU + uc + (ug + 2 * i) * 4);
                gk[i] = *(const float4*)(klnT + (size_t)(uc + ku_) * NB + kb + i * 64);
            }
        }
        #pragma unroll 4
        for (int u = 0; u < 16; ++u) {
            const float4 sv0 = *(const float4*)&smem[mo + u * 128 + s0];
            const float4 sv1 = *(const float4*)&smem[mo + u * 128 + s0 + 4];
            const float4 kv0 = *(const float4*)&smem[ko + u * 128 + b0a];   // 256B run: conflict-free
            const float4 kv1 = *(const float4*)&smem[ko + u * 128 + b0b];   // 256B run: conflict-free
            const float sv[8] = {sv0.x, sv0.y, sv0.z, sv0.w, sv1.x, sv1.y, sv1.z, sv1.w};
            const float kv[8] = {kv0.x, kv0.y, kv0.z, kv0.w, kv1.x, kv1.y, kv1.z, kv1.w};
            #pragma unroll
            for (int i = 0; i < 8; ++i)
                #pragma unroll
                for (int j = 0; j < 8; ++j)
                    acc[i][j] += sv[i] * kv[j];   // single fmac chain ascending u per (s,b)
        }
        __syncthreads();
    }

    // ---- phase 2: spill dot tile to LDS (aliases stage buffers; barrier-protected) ----
    #pragma unroll
    for (int i = 0; i < 8; ++i) {
        *(float4*)&smem[(s0 + i) * 128 + b0a] = make_float4(acc[i][0], acc[i][1], acc[i][2], acc[i][3]);
        *(float4*)&smem[(s0 + i) * 128 + b0b] = make_float4(acc[i][4], acc[i][5], acc[i][6], acc[i][7]);
    }
    __syncthreads();

    // ---- phase 3: per-slot softmax + usage + min (exact epilogue, lane = b-pair) ----
    const float wg = sigm(wgp[0]);
    const float omw = __fsub_rn(1.f, wg);
    unsigned long long lmin0 = ~0ULL, lmin1 = ~0ULL;
    #pragma unroll 2
    for (int i = 0; i < 32; ++i) {
        const int s = w * 32 + i;
        const int m = sb + s;
        const float2 dv = *(const float2*)&smem[s * 128 + 2 * l];
        const float rnv = rn_s[s];
        const float2 wrt = ((const float2*)(cwr_t + (size_t)m * NB))[l];
        const float2 wlu = ((const float2*)(cwlu_t + (size_t)m * NB))[l];
        const float2 wut = ((const float2*)(cwu_t + (size_t)m * NB))[l];
        const float c0 = dv.x / rnv, c1 = dv.y / rnv;
        float mx = fmaxf(c0, c1);
        #pragma unroll
        for (int d = 1; d < 64; d <<= 1) mx = fmaxf(mx, __shfl_xor(mx, d));
        const float e0 = expf(c0 - mx), e1 = expf(c1 - mx);
        float sm = e0 + e1;
        #pragma unroll
        for (int d = 1; d < 64; d <<= 1) sm += __shfl_xor(sm, d);
        const float w0 = e0 / sm, w1 = e1 / sm;
        const float cww0 = __fadd_rn(__fadd_rn(__fmul_rn(wg, wrt.x), omw), wlu.x);
        const float cww1 = __fadd_rn(__fadd_rn(__fmul_rn(wg, wrt.y), omw), wlu.y);
        const float cu0 = __fadd_rn(__fadd_rn(__fmul_rn(0.95f, wut.x), w0), cww0);
        const float cu1 = __fadd_rn(__fadd_rn(__fmul_rn(0.95f, wut.y), w1), cww1);
        ((float2*)(out + OUT_CWR))[(size_t)m * 64 + l] = make_float2(w0, w1);
        ((float2*)(out + OUT_CWU))[(size_t)m * 64 + l] = make_float2(cu0, cu1);
        const unsigned long long e0u = (((unsigned long long)fenc(cu0)) << 32) | (unsigned)m;
        const unsigned long long e1u = (((unsigned long long)fenc(cu1)) << 32) | (unsigned)m;
        lmin0 = (e0u < lmin0) ? e0u : lmin0;
        lmin1 = (e1u < lmin1) ? e1u : lmin1;
    }
    atomicMin(&minenc[2 * l], lmin0);
    atomicMin(&minenc[2 * l + 1], lmin1);
}

// ---------------- K3: global argmin (first-occurrence) ----------------
__global__ void k_argmin(const unsigned long long* __restrict__ minenc,
                         float* __restrict__ mins, unsigned* __restrict__ istar)
{
    __shared__ unsigned long long red[NB];
    const int t = threadIdx.x;
    const unsigned long long e = minenc[t];
    const unsigned enc32 = (unsigned)(e >> 32);
    mins[t] = fdec(enc32);
    red[t] = (((unsigned long long)enc32) << 32) | (unsigned)t;
    __syncthreads();
    for (int s = 64; s > 0; s >>= 1) {
        if (t < s) { const unsigned long long o = red[t + s]; if (o < red[t]) red[t] = o; }
        __syncthreads();
    }
    if (t == 0) {
        const unsigned bstar = (unsigned)(red[0] & 0xFFFFFFFFu);
        istar[0] = (unsigned)(minenc[bstar] & 0xFFFFFFFFu);
    }
}

// -------- K4a: memory = cww @ key (bf16 MFMA) + 128*keep*m (f32) + c_wlu (UNCHANGED R8) --------
__global__ __launch_bounds__(256, 2) void k_mem(
    const float* __restrict__ mT,
    const float* __restrict__ cwr_t, const float* __restrict__ cwlu_t,
    const float* __restrict__ wgp, const float* __restrict__ mins,
    const unsigned* __restrict__ istar_p, float* __restrict__ out)
{
    __shared__ unsigned short cwwb[128 * 136];   // [s][b] bf16, stride 136
    __shared__ unsigned short keyT[128 * 136];   // [u_local][b] bf16, one u-half
    const int t = threadIdx.x, w = t >> 6, l = t & 63;
    const int sb = blockIdx.x * 128;
    const float wg = sigm(wgp[0]);
    const float omw = __fsub_rn(1.f, wg);
    const int istar = (int)istar_p[0];

    // ---- S1: cww -> bf16 LDS; c_wlu -> global (exact f32 chain) ----
    {
        const int srow = t >> 5;
        const int bc = (t & 31) * 4;
        for (int it = 0; it < 16; ++it) {
            const int s = it * 8 + srow;
            const size_t row = (size_t)(sb + s) * NB + bc;
            const float4 wr = *(const float4*)(cwr_t + row);
            const float4 lu = *(const float4*)(cwlu_t + row);
            const float4 wu = *(const float4*)(out + OUT_CWU + row);
            float4 cw;
            cw.x = __fadd_rn(__fadd_rn(__fmul_rn(wg, wr.x), omw), lu.x);
            cw.y = __fadd_rn(__fadd_rn(__fmul_rn(wg, wr.y), omw), lu.y);
            cw.z = __fadd_rn(__fadd_rn(__fmul_rn(wg, wr.z), omw), lu.z);
            cw.w = __fadd_rn(__fadd_rn(__fmul_rn(wg, wr.w), omw), lu.w);
            ushort4 pk;
            pk.x = f2b(cw.x); pk.y = f2b(cw.y); pk.z = f2b(cw.z); pk.w = f2b(cw.w);
            *(ushort4*)&cwwb[s * 136 + bc] = pk;
            const float4 mb = *(const float4*)(mins + bc);
            float4 wl;
            wl.x = (wu.x <= mb.x) ? 1.f : 0.f;
            wl.y = (wu.y <= mb.y) ? 1.f : 0.f;
            wl.z = (wu.z <= mb.z) ? 1.f : 0.f;
            wl.w = (wu.w <= mb.w) ? 1.f : 0.f;
            *(float4*)(out + OUT_CWLU + row) = wl;
        }
    }

    const int rk = (l >> 4) * 8;
    const int rr = l & 15;

    for (int uh = 0; uh < 2; ++uh) {
        if (uh) __syncthreads();
        // ---- S2: keyT half uh: key[b][u] f32 -> bf16 LDS [u_local][b] ----
        {
            const int br = t >> 5;
            const int ko = (t & 31) * 4;
            for (int it = 0; it < 16; ++it) {
                const int b = it * 8 + br;
                const float4 kv = *(const float4*)(out + OUT_KEY + (size_t)b * NU + uh * 128 + ko);
                keyT[(ko + 0) * 136 + b] = f2b(kv.x);
                keyT[(ko + 1) * 136 + b] = f2b(kv.y);
                keyT[(ko + 2) * 136 + b] = f2b(kv.z);
                keyT[(ko + 3) * 136 + b] = f2b(kv.w);
            }
        }
        __syncthreads();

        // ---- MFMA: wave w -> s-tiles {2w, 2w+1}; 8 u-tiles; K=128 in 4 chunks ----
        floatx4 acc0[8], acc1[8];
        #pragma unroll
        for (int ut = 0; ut < 8; ++ut) {
            acc0[ut] = (floatx4){0.f, 0.f, 0.f, 0.f};
            acc1[ut] = (floatx4){0.f, 0.f, 0.f, 0.f};
        }
        #pragma unroll
        for (int kc = 0; kc < 4; ++kc) {
            const short8v a0 = *(const short8v*)&cwwb[(w * 32 + rr) * 136 + kc * 32 + rk];
            const short8v a1 = *(const short8v*)&cwwb[(w * 32 + 16 + rr) * 136 + kc * 32 + rk];
            #pragma unroll
            for (int ut = 0; ut < 8; ++ut) {
                const short8v bf = *(const short8v*)&keyT[(ut * 16 + rr) * 136 + kc * 32 + rk];
                acc0[ut] = __builtin_amdgcn_mfma_f32_16x16x32_bf16(a0, bf, acc0[ut], 0, 0, 0);
                acc1[ut] = __builtin_amdgcn_mfma_f32_16x16x32_bf16(a1, bf, acc1[ut], 0, 0, 0);
            }
        }

        // ---- epilogue: D + keep*128*m (exact f32) -> OUT_MEM ----
        #pragma unroll
        for (int ut = 0; ut < 8; ++ut) {
            const int gcol = uh * 128 + ut * 16 + rr;
            #pragma unroll
            for (int q = 0; q < 4; ++q) {
                const int grow0 = sb + w * 32 + (l >> 4) * 4 + q;
                const int grow1 = grow0 + 16;
                const float mv0 = mT[(size_t)grow0 * NU + gcol];
                const float mv1 = mT[(size_t)grow1 * NU + gcol];
                const float kf0 = (grow0 == istar) ? 0.f : 128.f;
                const float kf1 = (grow1 == istar) ? 0.f : 128.f;
                out[OUT_MEM + (size_t)grow0 * NU + gcol] = acc0[ut][q] + kf0 * mv0;
                out[OUT_MEM + (size_t)grow1 * NU + gcol] = acc1[ut][q] + kf1 * mv1;
            }
        }
    }
}

// -------- K4b: read = c_wr.T @ m_tm1 via bf16 MFMA, fragments direct from global (UNCHANGED R10) --------
template <int USE_PART>
__global__ __launch_bounds__(256) void k_read(
    const float* __restrict__ mT, float* __restrict__ out, float* __restrict__ part)
{
    const int t = threadIdx.x, w = t >> 6, l = t & 63;
    const int r = blockIdx.x, ri = r >> 1, uh = r & 1;
    const int rk = (l >> 4) * 8, rr = l & 15;
    const float* cwr = out + OUT_CWR;

    floatx4 acc[2][8];
    #pragma unroll
    for (int bt = 0; bt < 2; ++bt)
        #pragma unroll
        for (int ut = 0; ut < 8; ++ut) acc[bt][ut] = (floatx4){0.f, 0.f, 0.f, 0.f};

    for (int c = 0; c < 8; ++c) {
        const size_t m0 = (size_t)(ri * 256 + c * 32 + rk);
        short8v a[2];
        #pragma unroll
        for (int bt = 0; bt < 2; ++bt) {
            const float* ap = cwr + m0 * NB + w * 32 + bt * 16 + rr;
            #pragma unroll
            for (int i = 0; i < 8; ++i) a[bt][i] = (short)f2b(ap[i * NB]);
        }
        short8v bf[8];
        #pragma unroll
        for (int ut = 0; ut < 8; ++ut) {
            const float* bp = mT + m0 * NU + uh * 128 + ut * 16 + rr;
            #pragma unroll
            for (int i = 0; i < 8; ++i) bf[ut][i] = (short)f2b(bp[i * NU]);
        }
        #pragma unroll
        for (int bt = 0; bt < 2; ++bt)
            #pragma unroll
            for (int ut = 0; ut < 8; ++ut)
                acc[bt][ut] = __builtin_amdgcn_mfma_f32_16x16x32_bf16(a[bt], bf[ut], acc[bt][ut], 0, 0, 0);
    }

    // D mapping (m89-verified): col = l&15, row = (l>>4)*4 + q
    if (USE_PART) {
        float* dst = part + (size_t)r * (128 * 128);
        #pragma unroll
        for (int bt = 0; bt < 2; ++bt)
            #pragma unroll
            for (int ut = 0; ut < 8; ++ut)
                #pragma unroll
                for (int q = 0; q < 4; ++q)
                    dst[(size_t)(w * 32 + bt * 16 + (l >> 4) * 4 + q) * 128 + ut * 16 + rr] = acc[bt][ut][q];
    } else {
        #pragma unroll
        for (int bt = 0; bt < 2; ++bt)
            #pragma unroll
            for (int ut = 0; ut < 8; ++ut)
                #pragma unroll
                for (int q = 0; q < 4; ++q)
                    atomicAdd(out + OUT_READ + (size_t)(w * 32 + bt * 16 + (l >> 4) * 4 + q) * NU
                                  + uh * 128 + ut * 16 + rr, acc[bt][ut][q]);
    }
}

// ---------------- K5: deterministic read reduction ----------------
__global__ __launch_bounds__(256) void k_redread(const float* __restrict__ part,
                                                 float* __restrict__ out)
{
    const int b = blockIdx.x, u = threadIdx.x;
    const int uh = u >> 7, ul = u & 127;
    float s = 0.f;
    #pragma unroll 4
    for (int ri = 0; ri < 256; ++ri)
        s += part[((size_t)(ri * 2 + uh) * 128 + b) * 128 + ul];
    out[OUT_READ + b * NU + u] = s;
}

extern "C" void kernel_launch(void* const* d_in, const int* in_sizes, int n_in,
                              void* d_out, int out_size, void* d_ws, size_t ws_size,
                              hipStream_t stream)
{
    const float* inputs    = (const float*)d_in[0];
    const float* r_tm1     = (const float*)d_in[1];
    const float* m_tm1     = (const float*)d_in[2];
    const float* c_wu_tm1  = (const float*)d_in[3];
    const float* c_wlu_tm1 = (const float*)d_in[4];
    const float* c_wr_tm1  = (const float*)d_in[5];
    const float* h_tm1     = (const float*)d_in[6];
    const float* cc_tm1    = (const float*)d_in[7];
    const float* Wk        = (const float*)d_in[8];
    const float* Wr        = (const float*)d_in[9];
    const float* bias      = (const float*)d_in[10];
    const float* wgate     = (const float*)d_in[11];
    float* out = (float*)d_out;
    char* ws = (char*)d_ws;

    float* klnT = (float*)(ws + WS_KLNT);
    unsigned long long* minenc = (unsigned long long*)(ws + WS_MINENC);
    float* mins = (float*)(ws + WS_MINS);
    unsigned* istar = (unsigned*)(ws + WS_ISTAR);
    float* part = (float*)(ws + WS_PART);
    const bool use_part = ws_size >= WS_PART + (size_t)512 * 128 * 128 * 4;

    hipLaunchKernelGGL(k_lstm, dim3(128), dim3(256), 0, stream,
                       inputs, r_tm1, h_tm1, cc_tm1, Wk, Wr, bias, out, klnT, minenc);
    hipLaunchKernelGGL(k_dot, dim3(512), dim3(256), 0, stream,
                       m_tm1, klnT, c_wr_tm1, c_wlu_tm1, c_wu_tm1, wgate, out, minenc);
    hipLaunchKernelGGL(k_argmin, dim3(1), dim3(128), 0, stream, minenc, mins, istar);
    hipLaunchKernelGGL(k_mem, dim3(512), dim3(256), 0, stream,
                       m_tm1, c_wr_tm1, c_wlu_tm1, wgate, mins, istar, out);
    if (use_part) {
        hipLaunchKernelGGL((k_read<1>), dim3(512), dim3(256), 0, stream, m_tm1, out, part);
        hipLaunchKernelGGL(k_redread, dim3(128), dim3(256), 0, stream, part, out);
    } else {
        hipLaunchKernelGGL((k_read<0>), dim3(512), dim3(256), 0, stream, m_tm1, out, part);
    }
}

// Round 12
// 401.226 us; speedup vs baseline: 1.1095x; 1.0018x over previous
//
#include <hip/hip_runtime.h>
#include <hip/hip_bf16.h>
#include <math.h>

#define NM 65536
#define NB 128
#define NU 256
#define ND 512

// ---- output layout (flat f32, reference return order) ----
constexpr size_t OUT_READ = 0;                      // [B,U]    32768
constexpr size_t OUT_MEM  = 32768;                  // [M,U]    16777216
constexpr size_t OUT_CWU  = OUT_MEM + 16777216;     // [M,B]    8388608
constexpr size_t OUT_CWLU = OUT_CWU + 8388608;      // [M,B]
constexpr size_t OUT_CWR  = OUT_CWLU + 8388608;     // [M,B]
constexpr size_t OUT_KEY  = OUT_CWR + 8388608;      // [B,U]
constexpr size_t OUT_CC   = OUT_KEY + 32768;        // [B,U]

// ---- ws layout (bytes) ----
constexpr size_t WS_KLNT   = 0;        // 32768 f32 (klnT[u][b])
constexpr size_t WS_MINENC = 131072;   // 128 u64
constexpr size_t WS_MINS   = 132096;   // 128 f32
constexpr size_t WS_ISTAR  = 132608;   // 1 u32
constexpr size_t WS_PART   = 135168;   // 512 * 16384 f32 read-partials (32 MB)

typedef __attribute__((ext_vector_type(8))) short short8v;   // 8 bf16 (4 VGPRs)
typedef __attribute__((ext_vector_type(4))) float floatx4;

__device__ __forceinline__ unsigned fenc(float x) {
    unsigned u = __float_as_uint(x);
    return (u & 0x80000000u) ? ~u : (u | 0x80000000u);
}
__device__ __forceinline__ float fdec(unsigned e) {
    unsigned u = (e & 0x80000000u) ? (e ^ 0x80000000u) : ~e;
    return __uint_as_float(u);
}
__device__ __forceinline__ float sigm(float x) { return 1.0f / (1.0f + expf(-x)); }
__device__ __forceinline__ unsigned short f2b(float f) {
    __hip_bfloat16 h = __float2bfloat16(f);      // RNE
    return *reinterpret_cast<unsigned short*>(&h);
}

// ---------------- K1: LSTM controller + normalized keys (UNCHANGED, numerics anchor) ----------------
__global__ __launch_bounds__(256) void k_lstm(
    const float* __restrict__ xin_g, const float* __restrict__ r_tm1,
    const float* __restrict__ h_tm1, const float* __restrict__ cc_tm1,
    const float* __restrict__ Wk, const float* __restrict__ Wr,
    const float* __restrict__ bias, float* __restrict__ out,
    float* __restrict__ klnT, unsigned long long* __restrict__ minenc)
{
    const int b = blockIdx.x, t = threadIdx.x;
    __shared__ float xin[ND + NU];
    __shared__ float hh[NU];
    __shared__ float red[NU];
    for (int k = t; k < ND; k += 256) xin[k] = xin_g[b * ND + k];
    xin[ND + t] = r_tm1[b * NU + t];
    hh[t] = h_tm1[b * NU + t];
    out[OUT_READ + b * NU + t] = 0.f;              // zero read region each launch
    if (b == 0 && t < NB) minenc[t] = ~0ULL;       // init argmin atomics
    __syncthreads();

    float zi = bias[t], zf = bias[NU + t], zc = bias[2 * NU + t], zo = bias[3 * NU + t];
    #pragma unroll 4
    for (int k = 0; k < ND + NU; ++k) {
        const float x = xin[k];
        const float* w = Wk + (size_t)k * (4 * NU);
        zi += x * w[t]; zf += x * w[NU + t]; zc += x * w[2 * NU + t]; zo += x * w[3 * NU + t];
    }
    #pragma unroll 4
    for (int k = 0; k < NU; ++k) {
        const float x = hh[k];
        const float* w = Wr + (size_t)k * (4 * NU);
        zi += x * w[t]; zf += x * w[NU + t]; zc += x * w[2 * NU + t]; zo += x * w[3 * NU + t];
    }
    const float gi = sigm(zi), gf = sigm(zf), gc = tanhf(zc), go = sigm(zo);
    const float cold = cc_tm1[b * NU + t];
    const float cn = __fadd_rn(__fmul_rn(gf, cold), __fmul_rn(gi, gc));
    const float hn = __fmul_rn(go, tanhf(cn));
    out[OUT_KEY + b * NU + t] = hn;
    out[OUT_CC + b * NU + t] = cn;
    red[t] = hn * hn;
    __syncthreads();
    for (int s = 128; s > 0; s >>= 1) { if (t < s) red[t] += red[t + s]; __syncthreads(); }
    const float nrm = sqrtf(fmaxf(red[0], 1e-12f));
    klnT[t * NB + b] = hn / nrm;   // transposed [u][b]
}

// ------------- K2: fused norm + cosine GEMM + batch-softmax + usage + min (UNCHANGED R11) -------------
__global__ __launch_bounds__(256, 2) void k_dot(
    const float* __restrict__ mT, const float* __restrict__ klnT,
    const float* __restrict__ cwr_t, const float* __restrict__ cwlu_t,
    const float* __restrict__ cwu_t, const float* __restrict__ wgp,
    float* __restrict__ out, unsigned long long* __restrict__ minenc)
{
    __shared__ float smem[16384];      // 64 KB: stage tiles (32 KB), later dot tile [128][128]
    __shared__ float rn_s[128];
    const int t = threadIdx.x, w = t >> 6, l = t & 63;
    const int tx = t & 15, ty = t >> 4;
    const int b0a = tx * 4, b0b = 64 + tx * 4;   // split b-columns (conflict-free kv reads)
    const int s0 = ty * 8;
    const int sb = blockIdx.x * 128;

    // ---- phase 0: row norms (bit-identical: lane-l float4 + xor tree) ----
    #pragma unroll 4
    for (int i = 0; i < 32; ++i) {
        const int s = w * 32 + i;
        const float4 mv = *(const float4*)(mT + (size_t)(sb + s) * NU + l * 4);
        float ss = mv.x * mv.x + mv.y * mv.y + mv.z * mv.z + mv.w * mv.w;
        #pragma unroll
        for (int d = 1; d < 64; d <<= 1) ss += __shfl_xor(ss, d);
        if (l == 0) rn_s[s] = sqrtf(fmaxf(ss, 1e-12f));   // wave-private write/read
    }

    // ---- phase 1: GEMM dot[s][b] = sum_u m[s][u] * kln[u][b] ----
    const int sl = t & 127, ug = t >> 7;       // ms stage: slot sl, u-halves
    const int ku_ = t >> 4, kb = (t & 15) * 4; // kl stage

    float acc[8][8];
    #pragma unroll
    for (int i = 0; i < 8; ++i)
        #pragma unroll
        for (int j = 0; j < 8; ++j) acc[i][j] = 0.f;

    float4 gm[2], gk[2];
    #pragma unroll
    for (int i = 0; i < 2; ++i) {
        gm[i] = *(const float4*)(mT + (size_t)(sb + sl) * NU + (ug + 2 * i) * 4);
        gk[i] = *(const float4*)(klnT + (size_t)ku_ * NB + kb + i * 64);
    }
    for (int c = 0; c < 16; ++c) {
        const int mo = (c & 1) * 2048;          // ms buffer offset
        const int ko = 4096 + (c & 1) * 2048;   // kl buffer offset
        #pragma unroll
        for (int i = 0; i < 2; ++i) {
            const int uo = (ug + 2 * i) * 4;
            smem[mo + (uo + 0) * 128 + sl] = gm[i].x;
            smem[mo + (uo + 1) * 128 + sl] = gm[i].y;
            smem[mo + (uo + 2) * 128 + sl] = gm[i].z;
            smem[mo + (uo + 3) * 128 + sl] = gm[i].w;
            *(float4*)&smem[ko + ku_ * 128 + kb + i * 64] = gk[i];
        }
        __syncthreads();
        if (c < 15) {   // prefetch next chunk into registers (overlaps compute)
            const int uc = (c + 1) * 16;
            #pragma unroll
            for (int i = 0; i < 2; ++i) {
                gm[i] = *(const float4*)(mT + (size_t)(sb + sl) * NU + uc + (ug + 2 * i) * 4);
                gk[i] = *(const float4*)(klnT + (size_t)(uc + ku_) * NB + kb + i * 64);
            }
        }
        #pragma unroll 4
        for (int u = 0; u < 16; ++u) {
            const float4 sv0 = *(const float4*)&smem[mo + u * 128 + s0];
            const float4 sv1 = *(const float4*)&smem[mo + u * 128 + s0 + 4];
            const float4 kv0 = *(const float4*)&smem[ko + u * 128 + b0a];   // 256B run: conflict-free
            const float4 kv1 = *(const float4*)&smem[ko + u * 128 + b0b];   // 256B run: conflict-free
            const float sv[8] = {sv0.x, sv0.y, sv0.z, sv0.w, sv1.x, sv1.y, sv1.z, sv1.w};
            const float kv[8] = {kv0.x, kv0.y, kv0.z, kv0.w, kv1.x, kv1.y, kv1.z, kv1.w};
            #pragma unroll
            for (int i = 0; i < 8; ++i)
                #pragma unroll
                for (int j = 0; j < 8; ++j)
                    acc[i][j] += sv[i] * kv[j];   // single fmac chain ascending u per (s,b)
        }
        __syncthreads();
    }

    // ---- phase 2: spill dot tile to LDS (aliases stage buffers; barrier-protected) ----
    #pragma unroll
    for (int i = 0; i < 8; ++i) {
        *(float4*)&smem[(s0 + i) * 128 + b0a] = make_float4(acc[i][0], acc[i][1], acc[i][2], acc[i][3]);
        *(float4*)&smem[(s0 + i) * 128 + b0b] = make_float4(acc[i][4], acc[i][5], acc[i][6], acc[i][7]);
    }
    __syncthreads();

    // ---- phase 3: per-slot softmax + usage + min (exact epilogue, lane = b-pair) ----
    const float wg = sigm(wgp[0]);
    const float omw = __fsub_rn(1.f, wg);
    unsigned long long lmin0 = ~0ULL, lmin1 = ~0ULL;
    #pragma unroll 2
    for (int i = 0; i < 32; ++i) {
        const int s = w * 32 + i;
        const int m = sb + s;
        const float2 dv = *(const float2*)&smem[s * 128 + 2 * l];
        const float rnv = rn_s[s];
        const float2 wrt = ((const float2*)(cwr_t + (size_t)m * NB))[l];
        const float2 wlu = ((const float2*)(cwlu_t + (size_t)m * NB))[l];
        const float2 wut = ((const float2*)(cwu_t + (size_t)m * NB))[l];
        const float c0 = dv.x / rnv, c1 = dv.y / rnv;
        float mx = fmaxf(c0, c1);
        #pragma unroll
        for (int d = 1; d < 64; d <<= 1) mx = fmaxf(mx, __shfl_xor(mx, d));
        const float e0 = expf(c0 - mx), e1 = expf(c1 - mx);
        float sm = e0 + e1;
        #pragma unroll
        for (int d = 1; d < 64; d <<= 1) sm += __shfl_xor(sm, d);
        const float w0 = e0 / sm, w1 = e1 / sm;
        const float cww0 = __fadd_rn(__fadd_rn(__fmul_rn(wg, wrt.x), omw), wlu.x);
        const float cww1 = __fadd_rn(__fadd_rn(__fmul_rn(wg, wrt.y), omw), wlu.y);
        const float cu0 = __fadd_rn(__fadd_rn(__fmul_rn(0.95f, wut.x), w0), cww0);
        const float cu1 = __fadd_rn(__fadd_rn(__fmul_rn(0.95f, wut.y), w1), cww1);
        ((float2*)(out + OUT_CWR))[(size_t)m * 64 + l] = make_float2(w0, w1);
        ((float2*)(out + OUT_CWU))[(size_t)m * 64 + l] = make_float2(cu0, cu1);
        const unsigned long long e0u = (((unsigned long long)fenc(cu0)) << 32) | (unsigned)m;
        const unsigned long long e1u = (((unsigned long long)fenc(cu1)) << 32) | (unsigned)m;
        lmin0 = (e0u < lmin0) ? e0u : lmin0;
        lmin1 = (e1u < lmin1) ? e1u : lmin1;
    }
    atomicMin(&minenc[2 * l], lmin0);
    atomicMin(&minenc[2 * l + 1], lmin1);
}

// ---------------- K3: global argmin (first-occurrence) ----------------
__global__ void k_argmin(const unsigned long long* __restrict__ minenc,
                         float* __restrict__ mins, unsigned* __restrict__ istar)
{
    __shared__ unsigned long long red[NB];
    const int t = threadIdx.x;
    const unsigned long long e = minenc[t];
    const unsigned enc32 = (unsigned)(e >> 32);
    mins[t] = fdec(enc32);
    red[t] = (((unsigned long long)enc32) << 32) | (unsigned)t;
    __syncthreads();
    for (int s = 64; s > 0; s >>= 1) {
        if (t < s) { const unsigned long long o = red[t + s]; if (o < red[t]) red[t] = o; }
        __syncthreads();
    }
    if (t == 0) {
        const unsigned bstar = (unsigned)(red[0] & 0xFFFFFFFFu);
        istar[0] = (unsigned)(minenc[bstar] & 0xFFFFFFFFu);
    }
}

// -------- K4a: memory = cww @ key (bf16 MFMA) + 128*keep*m (f32) + c_wlu --------
// R8 structure; epilogue now transposes D through per-wave scratch (freed keyT
// region) so mT reads / MEM writes are float4 (was 128 scattered dwords/thread).
// Arithmetic identical -> bit-identical output.
__global__ __launch_bounds__(256, 2) void k_mem(
    const float* __restrict__ mT,
    const float* __restrict__ cwr_t, const float* __restrict__ cwlu_t,
    const float* __restrict__ wgp, const float* __restrict__ mins,
    const unsigned* __restrict__ istar_p, float* __restrict__ out)
{
    __shared__ alignas(16) unsigned short cwwb[128 * 136];   // [s][b] bf16, stride 136
    __shared__ alignas(16) unsigned short keyT[128 * 136];   // [u_local][b] bf16; reused as f32 scratch
    const int t = threadIdx.x, w = t >> 6, l = t & 63;
    const int sb = blockIdx.x * 128;
    const float wg = sigm(wgp[0]);
    const float omw = __fsub_rn(1.f, wg);
    const int istar = (int)istar_p[0];

    // ---- S1: cww -> bf16 LDS; c_wlu -> global (exact f32 chain) ----
    {
        const int srow = t >> 5;
        const int bc = (t & 31) * 4;
        for (int it = 0; it < 16; ++it) {
            const int s = it * 8 + srow;
            const size_t row = (size_t)(sb + s) * NB + bc;
            const float4 wr = *(const float4*)(cwr_t + row);
            const float4 lu = *(const float4*)(cwlu_t + row);
            const float4 wu = *(const float4*)(out + OUT_CWU + row);
            float4 cw;
            cw.x = __fadd_rn(__fadd_rn(__fmul_rn(wg, wr.x), omw), lu.x);
            cw.y = __fadd_rn(__fadd_rn(__fmul_rn(wg, wr.y), omw), lu.y);
            cw.z = __fadd_rn(__fadd_rn(__fmul_rn(wg, wr.z), omw), lu.z);
            cw.w = __fadd_rn(__fadd_rn(__fmul_rn(wg, wr.w), omw), lu.w);
            ushort4 pk;
            pk.x = f2b(cw.x); pk.y = f2b(cw.y); pk.z = f2b(cw.z); pk.w = f2b(cw.w);
            *(ushort4*)&cwwb[s * 136 + bc] = pk;
            const float4 mb = *(const float4*)(mins + bc);
            float4 wl;
            wl.x = (wu.x <= mb.x) ? 1.f : 0.f;
            wl.y = (wu.y <= mb.y) ? 1.f : 0.f;
            wl.z = (wu.z <= mb.z) ? 1.f : 0.f;
            wl.w = (wu.w <= mb.w) ? 1.f : 0.f;
            *(float4*)(out + OUT_CWLU + row) = wl;
        }
    }

    const int rk = (l >> 4) * 8;
    const int rr = l & 15;

    for (int uh = 0; uh < 2; ++uh) {
        if (uh) __syncthreads();     // epilogue scratch reads done before re-staging keyT
        // ---- S2: keyT half uh: key[b][u] f32 -> bf16 LDS [u_local][b] ----
        {
            const int br = t >> 5;
            const int ko = (t & 31) * 4;
            for (int it = 0; it < 16; ++it) {
                const int b = it * 8 + br;
                const float4 kv = *(const float4*)(out + OUT_KEY + (size_t)b * NU + uh * 128 + ko);
                keyT[(ko + 0) * 136 + b] = f2b(kv.x);
                keyT[(ko + 1) * 136 + b] = f2b(kv.y);
                keyT[(ko + 2) * 136 + b] = f2b(kv.z);
                keyT[(ko + 3) * 136 + b] = f2b(kv.w);
            }
        }
        __syncthreads();

        // ---- MFMA: wave w -> s-tiles {2w, 2w+1}; 8 u-tiles; K=128 in 4 chunks ----
        floatx4 acc0[8], acc1[8];
        #pragma unroll
        for (int ut = 0; ut < 8; ++ut) {
            acc0[ut] = (floatx4){0.f, 0.f, 0.f, 0.f};
            acc1[ut] = (floatx4){0.f, 0.f, 0.f, 0.f};
        }
        #pragma unroll
        for (int kc = 0; kc < 4; ++kc) {
            const short8v a0 = *(const short8v*)&cwwb[(w * 32 + rr) * 136 + kc * 32 + rk];
            const short8v a1 = *(const short8v*)&cwwb[(w * 32 + 16 + rr) * 136 + kc * 32 + rk];
            #pragma unroll
            for (int ut = 0; ut < 8; ++ut) {
                const short8v bf = *(const short8v*)&keyT[(ut * 16 + rr) * 136 + kc * 32 + rk];
                acc0[ut] = __builtin_amdgcn_mfma_f32_16x16x32_bf16(a0, bf, acc0[ut], 0, 0, 0);
                acc1[ut] = __builtin_amdgcn_mfma_f32_16x16x32_bf16(a1, bf, acc1[ut], 0, 0, 0);
            }
        }

        // ---- epilogue: transpose D via per-wave scratch (keyT region), float4 I/O ----
        __syncthreads();                           // all waves done reading keyT
        float* scr = (float*)keyT + w * 2112;      // [16][132] f32, wave-private
        const int erow = l >> 2, ecb = (l & 3) * 4;
        #pragma unroll
        for (int bt = 0; bt < 2; ++bt) {
            #pragma unroll
            for (int ut = 0; ut < 8; ++ut)
                #pragma unroll
                for (int q = 0; q < 4; ++q)
                    scr[((l >> 4) * 4 + q) * 132 + ut * 16 + rr] =
                        (bt == 0) ? acc0[ut][q] : acc1[ut][q];
            // wave-private region + per-wave in-order DS => no barrier needed here
            const int gs = sb + w * 32 + bt * 16 + erow;
            const float kf = (gs == istar) ? 0.f : 128.f;
            #pragma unroll
            for (int j = 0; j < 8; ++j) {
                const float4 d = *(const float4*)&scr[erow * 132 + j * 16 + ecb];
                const float4 mv = *(const float4*)(mT + (size_t)gs * NU + uh * 128 + j * 16 + ecb);
                float4 o;
                o.x = d.x + kf * mv.x;
                o.y = d.y + kf * mv.y;
                o.z = d.z + kf * mv.z;
                o.w = d.w + kf * mv.w;
                *(float4*)(out + OUT_MEM + (size_t)gs * NU + uh * 128 + j * 16 + ecb) = o;
            }
        }
    }
}

// -------- K4b v3: read = c_wr.T @ m_tm1 via bf16 MFMA, LDS-staged transposed bf16 --------
// Per 32-slot chunk: coalesced float4 loads -> bf16 LDS [b][m]/[u][m] (stride 40 u16
// = 80B: 16B-aligned b128, ~2-way banks) -> fragments via 10 ds_read_b128 (was 80
// scalar global loads + 80 converts). Same bf16 values & MFMA order -> bit-identical.
template <int USE_PART>
__global__ __launch_bounds__(256) void k_read(
    const float* __restrict__ mT, float* __restrict__ out, float* __restrict__ part)
{
    __shared__ alignas(16) unsigned short cwrb[128 * 40];  // [b][m_local] bf16
    __shared__ alignas(16) unsigned short mb[128 * 40];    // [u_local][m_local] bf16
    const int t = threadIdx.x, w = t >> 6, l = t & 63;
    const int r = blockIdx.x, ri = r >> 1, uh = r & 1;
    const int rk = (l >> 4) * 8, rr = l & 15;
    const float* cwr = out + OUT_CWR;
    const int srow = t >> 3, sc = (t & 7) * 16;

    floatx4 acc[2][8];
    #pragma unroll
    for (int bt = 0; bt < 2; ++bt)
        #pragma unroll
        for (int ut = 0; ut < 8; ++ut) acc[bt][ut] = (floatx4){0.f, 0.f, 0.f, 0.f};

    for (int c = 0; c < 8; ++c) {
        const size_t m0 = (size_t)(ri * 256 + c * 32);
        #pragma unroll
        for (int q = 0; q < 4; ++q) {
            const float4 v = *(const float4*)(cwr + (m0 + srow) * NB + sc + q * 4);
            cwrb[(sc + q * 4 + 0) * 40 + srow] = f2b(v.x);
            cwrb[(sc + q * 4 + 1) * 40 + srow] = f2b(v.y);
            cwrb[(sc + q * 4 + 2) * 40 + srow] = f2b(v.z);
            cwrb[(sc + q * 4 + 3) * 40 + srow] = f2b(v.w);
            const float4 u = *(const float4*)(mT + (m0 + srow) * NU + uh * 128 + sc + q * 4);
            mb[(sc + q * 4 + 0) * 40 + srow] = f2b(u.x);
            mb[(sc + q * 4 + 1) * 40 + srow] = f2b(u.y);
            mb[(sc + q * 4 + 2) * 40 + srow] = f2b(u.z);
            mb[(sc + q * 4 + 3) * 40 + srow] = f2b(u.w);
        }
        __syncthreads();
        const short8v a0 = *(const short8v*)&cwrb[(w * 32 + rr) * 40 + rk];
        const short8v a1 = *(const short8v*)&cwrb[(w * 32 + 16 + rr) * 40 + rk];
        #pragma unroll
        for (int ut = 0; ut < 8; ++ut) {
            const short8v bf = *(const short8v*)&mb[(ut * 16 + rr) * 40 + rk];
            acc[0][ut] = __builtin_amdgcn_mfma_f32_16x16x32_bf16(a0, bf, acc[0][ut], 0, 0, 0);
            acc[1][ut] = __builtin_amdgcn_mfma_f32_16x16x32_bf16(a1, bf, acc[1][ut], 0, 0, 0);
        }
        __syncthreads();
    }

    // D mapping (m89-verified): col = l&15, row = (l>>4)*4 + q
    if (USE_PART) {
        float* dst = part + (size_t)r * (128 * 128);
        #pragma unroll
        for (int bt = 0; bt < 2; ++bt)
            #pragma unroll
            for (int ut = 0; ut < 8; ++ut)
                #pragma unroll
                for (int q = 0; q < 4; ++q)
                    dst[(size_t)(w * 32 + bt * 16 + (l >> 4) * 4 + q) * 128 + ut * 16 + rr] = acc[bt][ut][q];
    } else {
        #pragma unroll
        for (int bt = 0; bt < 2; ++bt)
            #pragma unroll
            for (int ut = 0; ut < 8; ++ut)
                #pragma unroll
                for (int q = 0; q < 4; ++q)
                    atomicAdd(out + OUT_READ + (size_t)(w * 32 + bt * 16 + (l >> 4) * 4 + q) * NU
                                  + uh * 128 + ut * 16 + rr, acc[bt][ut][q]);
    }
}

// ---------------- K5: deterministic read reduction ----------------
__global__ __launch_bounds__(256) void k_redread(const float* __restrict__ part,
                                                 float* __restrict__ out)
{
    const int b = blockIdx.x, u = threadIdx.x;
    const int uh = u >> 7, ul = u & 127;
    float s = 0.f;
    #pragma unroll 4
    for (int ri = 0; ri < 256; ++ri)
        s += part[((size_t)(ri * 2 + uh) * 128 + b) * 128 + ul];
    out[OUT_READ + b * NU + u] = s;
}

extern "C" void kernel_launch(void* const* d_in, const int* in_sizes, int n_in,
                              void* d_out, int out_size, void* d_ws, size_t ws_size,
                              hipStream_t stream)
{
    const float* inputs    = (const float*)d_in[0];
    const float* r_tm1     = (const float*)d_in[1];
    const float* m_tm1     = (const float*)d_in[2];
    const float* c_wu_tm1  = (const float*)d_in[3];
    const float* c_wlu_tm1 = (const float*)d_in[4];
    const float* c_wr_tm1  = (const float*)d_in[5];
    const float* h_tm1     = (const float*)d_in[6];
    const float* cc_tm1    = (const float*)d_in[7];
    const float* Wk        = (const float*)d_in[8];
    const float* Wr        = (const float*)d_in[9];
    const float* bias      = (const float*)d_in[10];
    const float* wgate     = (const float*)d_in[11];
    float* out = (float*)d_out;
    char* ws = (char*)d_ws;

    float* klnT = (float*)(ws + WS_KLNT);
    unsigned long long* minenc = (unsigned long long*)(ws + WS_MINENC);
    float* mins = (float*)(ws + WS_MINS);
    unsigned* istar = (unsigned*)(ws + WS_ISTAR);
    float* part = (float*)(ws + WS_PART);
    const bool use_part = ws_size >= WS_PART + (size_t)512 * 128 * 128 * 4;

    hipLaunchKernelGGL(k_lstm, dim3(128), dim3(256), 0, stream,
                       inputs, r_tm1, h_tm1, cc_tm1, Wk, Wr, bias, out, klnT, minenc);
    hipLaunchKernelGGL(k_dot, dim3(512), dim3(256), 0, stream,
                       m_tm1, klnT, c_wr_tm1, c_wlu_tm1, c_wu_tm1, wgate, out, minenc);
    hipLaunchKernelGGL(k_argmin, dim3(1), dim3(128), 0, stream, minenc, mins, istar);
    hipLaunchKernelGGL(k_mem, dim3(512), dim3(256), 0, stream,
                       m_tm1, c_wr_tm1, c_wlu_tm1, wgate, mins, istar, out);
    if (use_part) {
        hipLaunchKernelGGL((k_read<1>), dim3(512), dim3(256), 0, stream, m_tm1, out, part);
        hipLaunchKernelGGL(k_redread, dim3(128), dim3(256), 0, stream, part, out);
    } else {
        hipLaunchKernelGGL((k_read<0>), dim3(512), dim3(256), 0, stream, m_tm1, out, part);
    }
}